// Round 9
// baseline (320.411 us; speedup 1.0000x reference)
//
#include <hip/hip_runtime.h>
#include <hip/hip_bf16.h>

#define NROW 50000
#define NCOL 50000
#define DDIM 128
#define CAP  32   // slots per destination row

typedef __bf16 bf16_t;
typedef __bf16 bf16x2 __attribute__((ext_vector_type(2)));
typedef __bf16 bf16x8 __attribute__((ext_vector_type(8)));
typedef float  f32x4  __attribute__((ext_vector_type(4)));

__device__ __forceinline__ float lrelu(float v) { return v >= 0.f ? v : 0.01f * v; }

__device__ __forceinline__ float ldf(const void* p, size_t i, bool f) {
    return f ? ((const float*)p)[i] : (float)((const bf16_t*)p)[i];
}

// fi: >=0 -> flags[fi]; -1 -> forced f32; -2 -> forced bf16
__device__ __forceinline__ bool dtf(const int* flags, int fi) {
    return (fi == -1) ? true : (fi == -2) ? false : (flags[fi] != 0);
}

// ---------------- D1: dtype detect (18 blocks) + zero counts ---------------
struct TensorTab { const void* p[18]; int n[18]; };

__global__ __launch_bounds__(256) void detect_zero(TensorTab T, int* flags,
                                                   int* z, int zn)
{
    const int tid = threadIdx.x;
    if (blockIdx.x >= 18) {                  // zero countsA|ovCntA|countsB|ovCntB
        int i = (blockIdx.x - 18) * 256 + tid;
        if (i < zn) z[i] = 0;
        return;
    }
    __shared__ int vb, vf;
    const int t = blockIdx.x;
    if (tid == 0) { vb = 0; vf = 0; }
    __syncthreads();
    const int n = T.n[t];
    const bool isFloatArr = (t != 2 && t != 3 && t != 5 && t != 6) && n >= 2;
    if (isFloatArr) {
        int nw = n / 2;
        int wi = (int)(((long long)tid * nw) >> 8);
        unsigned w = ((const unsigned*)T.p[t])[wi];
        unsigned low = w & 0xffffu;
        if (low) {
            int e = (int)((low >> 7) & 0xffu);
            if (e >= 90 && e <= 141) atomicAdd(&vb, 1);
            else                     atomicAdd(&vf, 1);
        }
    }
    __syncthreads();
    if (tid == 0) flags[t] = (isFloatArr && vf > vb) ? 1 : 0; // 1 = f32
}

// ---------------- fill: 4B edge-id slots (halves write-line traffic) --------
__device__ __forceinline__ void fill_edges_id(
    int e, const int* __restrict__ dst, int nE, int* __restrict__ counts,
    int* __restrict__ slots, int* __restrict__ ovCnt, int* __restrict__ ovList)
{
    if (e >= nE) return;
    int d = dst[e];
    int pos = atomicAdd(&counts[d], 1);
    if (pos < CAP) {
        slots[(size_t)d * CAP + pos] = e;
    } else {
        int k = atomicAdd(ovCnt, 1);         // capacity == nE
        ovList[k] = e;
    }
}

// ---------------- A2-legacy fill: packed (src,w) int2 slots -----------------
__device__ __forceinline__ void fill_edges(
    int e, const int* __restrict__ dst, const int* __restrict__ srcArr,
    const void* __restrict__ wArr, int nE, int* __restrict__ counts,
    int2* __restrict__ slots2, int* __restrict__ ovCnt,
    int* __restrict__ ovList, bool fW)
{
    if (e >= nE) return;
    int d = dst[e];
    int pos = atomicAdd(&counts[d], 1);
    if (pos < CAP) {
        int2 pk;
        pk.x = srcArr[e];
        pk.y = __float_as_int(ldf(wArr, e, fW));
        slots2[(size_t)d * CAP + pos] = pk;
    } else {
        int k = atomicAdd(ovCnt, 1);
        ovList[k] = e;
    }
}

struct WPtrs { const void* W[4]; int fi[4]; };

__device__ __forceinline__ void prep_one(WPtrs P, const int* flags,
                                         __bf16* wfp, int slot)
{
    if (slot >= 4 * 2048) return;
    int m = slot >> 11, sIdx = slot & 2047;
    bool f = flags[P.fi[m]] != 0;
    int l = sIdx & 63, combo = sIdx >> 6;
    int ct = combo >> 2, kk = combo & 3;
    int col  = ct * 16 + (l & 15);
    int krow = kk * 32 + (l >> 4) * 8;
    bf16x8 v;
#pragma unroll
    for (int j = 0; j < 8; ++j)
        v[j] = (__bf16)ldf(P.W[m], (size_t)(krow + j) * DDIM + col, f);
    ((bf16x8*)wfp)[slot] = v;
}

__device__ __forceinline__ void convert_one(const void* __restrict__ feat,
                                            __bf16* __restrict__ cbuf,
                                            int i, int n8, bool f)
{
    if (i >= n8) return;
    bf16x8 v;
    if (f) {
        f32x4 a = ((const f32x4*)feat)[i * 2];
        f32x4 c = ((const f32x4*)feat)[i * 2 + 1];
#pragma unroll
        for (int j = 0; j < 4; ++j) { v[j] = (__bf16)a[j]; v[j + 4] = (__bf16)c[j]; }
    } else {
        v = ((const bf16x8*)feat)[i];
    }
    ((bf16x8*)cbuf)[i] = v;
}

// ---------------- D2 (A4): convert || fillA interleaved 4:3, prep tail ------
__global__ __launch_bounds__(1024) void prep_fill_i2(
    WPtrs P, const int* __restrict__ flags, __bf16* __restrict__ wfp,
    const void* __restrict__ feat, __bf16* __restrict__ cbuf, int n8,
    int fiFeat, int cb, int eb, int K7,
    const int* __restrict__ f_dst, int f_nE, int* __restrict__ f_counts,
    int* __restrict__ f_slots, int* __restrict__ f_ovCnt,
    int* __restrict__ f_ovList)
{
    const int g = blockIdx.x;
    const int tid = threadIdx.x;
    if (g >= K7) {                            // weight B-frag prep
        prep_one(P, flags, wfp, (g - K7) * 1024 + tid);
        return;
    }
    int grp = g / 7, rem = g % 7;
    if (rem < 4) {                            // convert feat table to bf16
        int b = grp * 4 + rem;
        if (b >= cb) return;
        convert_one(feat, cbuf, b * 1024 + tid, n8, dtf(flags, fiFeat));
    } else {                                  // fill stage-1 buckets
        int b = grp * 3 + (rem - 4);
        if (b >= eb) return;
        fill_edges_id(b * 1024 + tid, f_dst, f_nE, f_counts, f_slots,
                      f_ovCnt, f_ovList);
    }
}

// ---------------- A4: fused segsum + MLP, 16-wave blocks --------------------
// Block = 1024 threads = 16 waves, 16 rows. Phase S: ONE ROW PER WAVE (full
// standalone-segsum gather parallelism: 50K gather waves, 4-deep pipeline).
// MLP: waves 0-7 each own one 16-col tile for both layers (4+4 weight frags
// register-resident). Waves 8-15 idle through the two uniform syncs.
// fill role (interleaved 4:3): bucket-fill for the NEXT stage (4B edge ids).
template <bool RESIDUAL, bool HOUT>
__global__ __launch_bounds__(1024) void mlp_fused2(
    const __bf16* __restrict__ gsrc, const int* __restrict__ counts,
    const int* __restrict__ slots, const int* __restrict__ srcArr,
    const int* __restrict__ dstArr, const void* __restrict__ wArr,
    const int* __restrict__ ovList, const int* __restrict__ ovCount, int fiW,
    const void* __restrict__ feat, const void* __restrict__ b1,
    const void* __restrict__ b2, const void* __restrict__ epsp,
    float* __restrict__ out, int N, const int* __restrict__ flags,
    int fiFeat, int fiB1, int fiB2, int fiEps,
    const __bf16* __restrict__ pW1, const __bf16* __restrict__ pW2,
    __bf16* __restrict__ hout,
    int mlpBlocks, int fillBlocks,
    const int* __restrict__ f_dst, int f_nE, int* __restrict__ f_counts,
    int* __restrict__ f_slots, int* __restrict__ f_ovCnt,
    int* __restrict__ f_ovList)
{
    __shared__ alignas(16) __bf16 At[16 * 136];   // A tile (later: hout stage)
    __shared__ alignas(16) __bf16 H1[16 * 136];   // h1 exchange tile

    const int tid = threadIdx.x;
    int bid;
    if (f_dst) {                              // interleaved roles, 4 mlp : 3 fill
        int grp = (int)blockIdx.x / 7, rem = (int)blockIdx.x % 7;
        if (rem >= 4) {
            int b = grp * 3 + (rem - 4);
            if (b < fillBlocks)
                fill_edges_id(b * 1024 + tid, f_dst, f_nE, f_counts,
                              f_slots, f_ovCnt, f_ovList);
            return;
        }
        bid = grp * 4 + rem;
        if (bid >= mlpBlocks) return;
    } else {
        bid = blockIdx.x;
        if (bid >= mlpBlocks) return;
    }

    const bool fF  = flags[fiFeat] != 0;
    const bool fB1 = flags[fiB1] != 0;
    const bool fB2 = flags[fiB2] != 0;
    const bool fE  = flags[fiEps] != 0;
    const bool fW  = dtf(flags, fiW);

    const int lane = tid & 63;
    const int wave = tid >> 6;                // 0..15
    const int quad = lane >> 4;
    const int r    = lane & 15;
    const int rowBase = bid * 16;
    const float eps1 = 1.f + ldf(epsp, 0, fE);

    // ---- Phase S: gather, ONE row per wave (4-deep pipeline) ----
    {
        const bf16x2* fb = (const bf16x2*)gsrc;
        int row = rowBase + wave;
        bf16x2 o;
        if (row < N) {
            int cntRaw = counts[row];
            int cnt = cntRaw > CAP ? CAP : cntRaw;
            int sr = 0; float wv = 0.f;
            if (lane < cnt) {                 // lane-parallel e -> src,w prefetch
                int e = slots[(size_t)row * CAP + lane];
                sr = srcArr[e];
                wv = ldf(wArr, e, fW);
            }
            float2 acc0 = {0.f, 0.f}, acc1 = {0.f, 0.f};
            int i = 0;
            for (; i + 4 <= cnt; i += 4) {
                int   a0 = __shfl(sr, i),     a1 = __shfl(sr, i + 1);
                int   a2 = __shfl(sr, i + 2), a3 = __shfl(sr, i + 3);
                float w0 = __shfl(wv, i),     w1 = __shfl(wv, i + 1);
                float w2 = __shfl(wv, i + 2), w3 = __shfl(wv, i + 3);
                bf16x2 v0 = fb[(size_t)a0 * 64 + lane];
                bf16x2 v1 = fb[(size_t)a1 * 64 + lane];
                bf16x2 v2 = fb[(size_t)a2 * 64 + lane];
                bf16x2 v3 = fb[(size_t)a3 * 64 + lane];
                acc0.x += (float)v0[0] * w0; acc0.y += (float)v0[1] * w0;
                acc1.x += (float)v1[0] * w1; acc1.y += (float)v1[1] * w1;
                acc0.x += (float)v2[0] * w2; acc0.y += (float)v2[1] * w2;
                acc1.x += (float)v3[0] * w3; acc1.y += (float)v3[1] * w3;
            }
            for (; i < cnt; ++i) {
                int   a0 = __shfl(sr, i);
                float w0 = __shfl(wv, i);
                bf16x2 v0 = fb[(size_t)a0 * 64 + lane];
                acc0.x += (float)v0[0] * w0; acc0.y += (float)v0[1] * w0;
            }
            if (cntRaw > CAP) {               // rare: exact overflow scan
                int nOv = *ovCount;
                for (int k = 0; k < nOv; ++k) {
                    int e = ovList[k];
                    if (dstArr[e] == row) {
                        int s = srcArr[e];
                        float wf = ldf(wArr, e, fW);
                        bf16x2 v = fb[(size_t)s * 64 + lane];
                        acc0.x += (float)v[0] * wf;
                        acc0.y += (float)v[1] * wf;
                    }
                }
            }
            float ax = acc0.x + acc1.x, ay = acc0.y + acc1.y;
            float f0, f1;
            if (fF) {
                float2 fv = ((const float2*)((const float*)feat +
                             (size_t)row * DDIM))[lane];
                f0 = fv.x; f1 = fv.y;
            } else {
                bf16x2 fv = ((const bf16x2*)((const bf16_t*)feat +
                             (size_t)row * DDIM))[lane];
                f0 = (float)fv[0]; f1 = (float)fv[1];
            }
            o[0] = (__bf16)(f0 * eps1 + ax);
            o[1] = (__bf16)(f1 * eps1 + ay);
        } else {
            o[0] = (__bf16)0.f; o[1] = (__bf16)0.f;
        }
        *(bf16x2*)&At[wave * 136 + lane * 2] = o;
    }
    __syncthreads();

    // ---- layer 1: waves 0-7, one 16-col tile each ----
    const int ct = wave;
    if (wave < 8) {
        bf16x8 a[4];
#pragma unroll
        for (int kk = 0; kk < 4; ++kk)
            a[kk] = *(const bf16x8*)&At[r * 136 + kk * 32 + quad * 8];
        const bf16x8* pw1v = (const bf16x8*)pW1;
        bf16x8 w1f[4];
#pragma unroll
        for (int kk = 0; kk < 4; ++kk)
            w1f[kk] = pw1v[(ct * 4 + kk) * 64 + lane];
        float b1v = ldf(b1, ct * 16 + r, fB1);
        f32x4 acc = {0.f, 0.f, 0.f, 0.f};
#pragma unroll
        for (int kk = 0; kk < 4; ++kk)
            acc = __builtin_amdgcn_mfma_f32_16x16x32_bf16(a[kk], w1f[kk], acc, 0, 0, 0);
#pragma unroll
        for (int gg = 0; gg < 4; ++gg)
            H1[(quad * 4 + gg) * 136 + ct * 16 + r] = (__bf16)lrelu(acc[gg] + b1v);
    }
    __syncthreads();

    // ---- layer 2: waves 0-7 -> out (+residual); HOUT: stage bf16 h in At ---
    if (wave < 8) {
        bf16x8 a2[4];
#pragma unroll
        for (int kk = 0; kk < 4; ++kk)
            a2[kk] = *(const bf16x8*)&H1[r * 136 + kk * 32 + quad * 8];
        const bf16x8* pw2v = (const bf16x8*)pW2;
        bf16x8 w2f[4];
#pragma unroll
        for (int kk = 0; kk < 4; ++kk)
            w2f[kk] = pw2v[(ct * 4 + kk) * 64 + lane];
        float b2v = ldf(b2, ct * 16 + r, fB2);
        f32x4 acc = {0.f, 0.f, 0.f, 0.f};
#pragma unroll
        for (int kk = 0; kk < 4; ++kk)
            acc = __builtin_amdgcn_mfma_f32_16x16x32_bf16(a2[kk], w2f[kk], acc, 0, 0, 0);
#pragma unroll
        for (int gg = 0; gg < 4; ++gg) {
            int row = rowBase + quad * 4 + gg;
            float v = lrelu(acc[gg] + b2v);
            if (HOUT)
                At[(quad * 4 + gg) * 136 + ct * 16 + r] = (__bf16)v;
            if (row < N) {
                int col = ct * 16 + r;
                if (RESIDUAL) v += ldf(feat, (size_t)row * DDIM + col, fF);
                out[(size_t)row * DDIM + col] = v;
            }
        }
    }

    // ---- cooperative coalesced hout store ----
    if (HOUT) {
        __syncthreads();
        if (tid < 256) {                      // 16 rows x 16 chunks of bf16x8
            int row = tid >> 4;
            int k0  = (tid & 15) * 8;
            int g   = rowBase + row;
            if (g < N)
                *(bf16x8*)&hout[(size_t)g * DDIM + k0] =
                    *(const bf16x8*)&At[row * 136 + k0];
        }
    }
}

// =================== round-7 tier-A2 fallback kernels (proven) ==============
__global__ __launch_bounds__(256) void prep_fill(
    WPtrs P, const int* __restrict__ flags, __bf16* __restrict__ wfp,
    const void* __restrict__ feat, __bf16* __restrict__ cbuf, int n8,
    int fiFeat, int cblocks,
    const int* __restrict__ f_dst, const int* __restrict__ f_src,
    const void* __restrict__ f_w, int f_nE, int* __restrict__ f_counts,
    int2* __restrict__ f_slots2, int* __restrict__ f_ovCnt,
    int* __restrict__ f_ovList, int f_fiW)
{
    const int b = blockIdx.x;
    const int tid = threadIdx.x;
    if (b < cblocks) {
        convert_one(feat, cbuf, b * 256 + tid, n8, dtf(flags, fiFeat));
    } else if (b < cblocks + 32) {
        prep_one(P, flags, wfp, (b - cblocks) * 256 + tid);
    } else {
        int e = (b - cblocks - 32) * 256 + tid;
        fill_edges(e, f_dst, f_src, f_w, f_nE, f_counts, f_slots2,
                   f_ovCnt, f_ovList, dtf(flags, f_fiW));
    }
}

__global__ __launch_bounds__(256) void segsum_scan(
    const __bf16* __restrict__ gsrc, const int* __restrict__ counts,
    const int2* __restrict__ slots2, float* __restrict__ agg, int nRows,
    const int* __restrict__ srcArr, const int* __restrict__ dstArr,
    const void* __restrict__ wArr, const int* __restrict__ ovList,
    const int* __restrict__ ovCount, const int* __restrict__ flags, int fiW)
{
    int row = blockIdx.x * 4 + (threadIdx.x >> 6);
    if (row >= nRows) return;
    int lane = threadIdx.x & 63;

    int cntRaw = counts[row];
    int cnt = cntRaw > CAP ? CAP : cntRaw;

    int sr = 0; float wv = 0.f;
    if (lane < cnt) {
        int2 pk = slots2[(size_t)row * CAP + lane];
        sr = pk.x;
        wv = __int_as_float(pk.y);
    }

    float2* ap = (float2*)(agg + (size_t)row * DDIM) + lane;
    float2 acc0 = {0.f, 0.f}, acc1 = {0.f, 0.f};

    const bf16x2* fb = (const bf16x2*)gsrc;
    int i = 0;
    for (; i + 4 <= cnt; i += 4) {
        int   a0 = __shfl(sr, i),     a1 = __shfl(sr, i + 1);
        int   a2 = __shfl(sr, i + 2), a3 = __shfl(sr, i + 3);
        float w0 = __shfl(wv, i),     w1 = __shfl(wv, i + 1);
        float w2 = __shfl(wv, i + 2), w3 = __shfl(wv, i + 3);
        bf16x2 v0 = fb[(size_t)a0 * 64 + lane];
        bf16x2 v1 = fb[(size_t)a1 * 64 + lane];
        bf16x2 v2 = fb[(size_t)a2 * 64 + lane];
        bf16x2 v3 = fb[(size_t)a3 * 64 + lane];
        acc0.x += (float)v0[0] * w0; acc0.y += (float)v0[1] * w0;
        acc1.x += (float)v1[0] * w1; acc1.y += (float)v1[1] * w1;
        acc0.x += (float)v2[0] * w2; acc0.y += (float)v2[1] * w2;
        acc1.x += (float)v3[0] * w3; acc1.y += (float)v3[1] * w3;
    }
    for (; i < cnt; ++i) {
        int   a0 = __shfl(sr, i);
        float w0 = __shfl(wv, i);
        bf16x2 v0 = fb[(size_t)a0 * 64 + lane];
        acc0.x += (float)v0[0] * w0; acc0.y += (float)v0[1] * w0;
    }
    if (cntRaw > CAP) {
        const bool fW = dtf(flags, fiW);
        int nOv = *ovCount;
        for (int k = 0; k < nOv; ++k) {
            int e = ovList[k];
            if (dstArr[e] == row) {
                int s = srcArr[e];
                float wf = ldf(wArr, e, fW);
                bf16x2 v = fb[(size_t)s * 64 + lane];
                acc0.x += (float)v[0] * wf; acc0.y += (float)v[1] * wf;
            }
        }
    }
    acc0.x += acc1.x; acc0.y += acc1.y;
    *ap = acc0;
}

template <bool RESIDUAL, bool HOUT>
__global__ __launch_bounds__(256) void mlp_cs(
    const void* __restrict__ feat, const float* __restrict__ agg,
    const void* __restrict__ b1, const void* __restrict__ b2,
    const void* __restrict__ epsp, float* __restrict__ out, int N,
    const int* __restrict__ flags, int fiFeat, int fiB1, int fiB2, int fiEps,
    const __bf16* __restrict__ pW1, const __bf16* __restrict__ pW2,
    __bf16* __restrict__ hout,
    int mblocks,
    const int* __restrict__ f_dst, const int* __restrict__ f_src,
    const void* __restrict__ f_w, int f_nE, int* __restrict__ f_counts,
    int2* __restrict__ f_slots2, int* __restrict__ f_ovCnt,
    int* __restrict__ f_ovList, int f_fiW)
{
    __shared__ alignas(16) __bf16 At[16 * 136];
    __shared__ alignas(16) __bf16 H1[16 * 136];

    const int tid = threadIdx.x;
    if (f_dst && (int)blockIdx.x >= mblocks) {
        int e = ((int)blockIdx.x - mblocks) * 256 + tid;
        fill_edges(e, f_dst, f_src, f_w, f_nE, f_counts, f_slots2,
                   f_ovCnt, f_ovList, dtf(flags, f_fiW));
        return;
    }

    const bool fF  = flags[fiFeat] != 0;
    const bool fB1 = flags[fiB1] != 0;
    const bool fB2 = flags[fiB2] != 0;
    const bool fE  = flags[fiEps] != 0;

    const int lane = tid & 63;
    const int wave = tid >> 6;
    const int quad = lane >> 4;
    const int r    = lane & 15;
    const int rowBase = blockIdx.x * 16;
    const float eps1 = 1.f + ldf(epsp, 0, fE);

    {
        int row = tid >> 4;
        int k0  = (tid & 15) * 8;
        int g   = rowBase + row;
        bf16x8 av;
        if (g < N) {
            size_t base = (size_t)g * DDIM + k0;
            const f32x4* gp = (const f32x4*)(agg + base);
            f32x4 g0 = gp[0], g1 = gp[1];
            if (fF) {
                const f32x4* fp = (const f32x4*)((const float*)feat + base);
                f32x4 f0 = fp[0], f1 = fp[1];
#pragma unroll
                for (int j = 0; j < 4; ++j) {
                    av[j]     = (__bf16)(f0[j] * eps1 + g0[j]);
                    av[j + 4] = (__bf16)(f1[j] * eps1 + g1[j]);
                }
            } else {
                bf16x8 fv = *(const bf16x8*)((const bf16_t*)feat + base);
#pragma unroll
                for (int j = 0; j < 4; ++j) {
                    av[j]     = (__bf16)((float)fv[j]     * eps1 + g0[j]);
                    av[j + 4] = (__bf16)((float)fv[j + 4] * eps1 + g1[j]);
                }
            }
        } else {
#pragma unroll
            for (int j = 0; j < 8; ++j) av[j] = (__bf16)0.f;
        }
        *(bf16x8*)&At[row * 136 + k0] = av;
    }
    __syncthreads();

    bf16x8 a[4];
#pragma unroll
    for (int kk = 0; kk < 4; ++kk)
        a[kk] = *(const bf16x8*)&At[r * 136 + kk * 32 + quad * 8];

    const int ct0 = wave * 2, ct1 = ct0 + 1;

    const bf16x8* pw1v = (const bf16x8*)pW1;
    bf16x8 wfa[4], wfb[4];
#pragma unroll
    for (int kk = 0; kk < 4; ++kk) {
        wfa[kk] = pw1v[(ct0 * 4 + kk) * 64 + lane];
        wfb[kk] = pw1v[(ct1 * 4 + kk) * 64 + lane];
    }
    float b1a = ldf(b1, ct0 * 16 + r, fB1);
    float b1b = ldf(b1, ct1 * 16 + r, fB1);

    {
        f32x4 acc = {0.f, 0.f, 0.f, 0.f};
#pragma unroll
        for (int kk = 0; kk < 4; ++kk)
            acc = __builtin_amdgcn_mfma_f32_16x16x32_bf16(a[kk], wfa[kk], acc, 0, 0, 0);
#pragma unroll
        for (int gg = 0; gg < 4; ++gg)
            H1[(quad * 4 + gg) * 136 + ct0 * 16 + r] = (__bf16)lrelu(acc[gg] + b1a);
    }
    {
        f32x4 acc = {0.f, 0.f, 0.f, 0.f};
#pragma unroll
        for (int kk = 0; kk < 4; ++kk)
            acc = __builtin_amdgcn_mfma_f32_16x16x32_bf16(a[kk], wfb[kk], acc, 0, 0, 0);
#pragma unroll
        for (int gg = 0; gg < 4; ++gg)
            H1[(quad * 4 + gg) * 136 + ct1 * 16 + r] = (__bf16)lrelu(acc[gg] + b1b);
    }
    __syncthreads();

    bf16x8 a2[4];
#pragma unroll
    for (int kk = 0; kk < 4; ++kk)
        a2[kk] = *(const bf16x8*)&H1[r * 136 + kk * 32 + quad * 8];

    const bf16x8* pw2v = (const bf16x8*)pW2;
#pragma unroll
    for (int kk = 0; kk < 4; ++kk) {
        wfa[kk] = pw2v[(ct0 * 4 + kk) * 64 + lane];
        wfb[kk] = pw2v[(ct1 * 4 + kk) * 64 + lane];
    }
    float b2a = ldf(b2, ct0 * 16 + r, fB2);
    float b2b = ldf(b2, ct1 * 16 + r, fB2);

#pragma unroll
    for (int cp = 0; cp < 2; ++cp) {
        const int ct = cp ? ct1 : ct0;
        f32x4 acc = {0.f, 0.f, 0.f, 0.f};
#pragma unroll
        for (int kk = 0; kk < 4; ++kk)
            acc = __builtin_amdgcn_mfma_f32_16x16x32_bf16(
                a2[kk], cp ? wfb[kk] : wfa[kk], acc, 0, 0, 0);
        float bias = cp ? b2b : b2a;
#pragma unroll
        for (int gg = 0; gg < 4; ++gg) {
            int row = rowBase + quad * 4 + gg;
            float v = lrelu(acc[gg] + bias);
            if (HOUT)
                At[(quad * 4 + gg) * 136 + ct * 16 + r] = (__bf16)v;
            if (row < N) {
                int col = ct * 16 + r;
                if (RESIDUAL) v += ldf(feat, (size_t)row * DDIM + col, fF);
                out[(size_t)row * DDIM + col] = v;
            }
        }
    }

    if (HOUT) {
        __syncthreads();
        int row = tid >> 4;
        int k0  = (tid & 15) * 8;
        int g   = rowBase + row;
        if (g < N)
            *(bf16x8*)&hout[(size_t)g * DDIM + k0] =
                *(const bf16x8*)&At[row * 136 + k0];
    }
}

// ======================= legacy kernels (ws-too-small) ======================
__global__ __launch_bounds__(256) void scatter_any(
    const void* __restrict__ feat, const int* __restrict__ src,
    const int* __restrict__ dst, const void* __restrict__ w,
    float* __restrict__ agg, int nE,
    const int* __restrict__ flags, int fiFeat, int fiW)
{
    const bool fF = dtf(flags, fiFeat);
    const bool fW = dtf(flags, fiW);
    int g = blockIdx.x * 256 + threadIdx.x;
    int e = g >> 5;
    if (e >= nE) return;
    int c = (g & 31) << 2;
    int s = src[e], d = dst[e];
    float wf = ldf(w, e, fW);
    size_t base = (size_t)s * DDIM + c;
    float* ap = agg + (size_t)d * DDIM + c;
    unsafeAtomicAdd(ap + 0, ldf(feat, base + 0, fF) * wf);
    unsafeAtomicAdd(ap + 1, ldf(feat, base + 1, fF) * wf);
    unsafeAtomicAdd(ap + 2, ldf(feat, base + 2, fF) * wf);
    unsafeAtomicAdd(ap + 3, ldf(feat, base + 3, fF) * wf);
}

__global__ __launch_bounds__(256) void residual_add(
    float* __restrict__ out, const void* __restrict__ feat, int n4,
    const int* __restrict__ flags, int fiFeat)
{
    const bool fF = flags[fiFeat] != 0;
    int i = blockIdx.x * 256 + threadIdx.x;
    if (i >= n4) return;
    f32x4 o = ((const f32x4*)out)[i];
    f32x4 r;
#pragma unroll
    for (int j = 0; j < 4; ++j) r[j] = o[j] + ldf(feat, (size_t)i * 4 + j, fF);
    ((f32x4*)out)[i] = r;
}

__device__ __forceinline__ void fill_wfrag(const void* __restrict__ W, bool f,
                                           __bf16* wf, int tid)
{
#pragma unroll
    for (int i = 0; i < 8; ++i) {
        int sIdx  = tid + i * 256;
        int l     = sIdx & 63;
        int combo = sIdx >> 6;
        int ct = combo >> 2, kk = combo & 3;
        int col  = ct * 16 + (l & 15);
        int krow = kk * 32 + (l >> 4) * 8;
        __bf16* dp = wf + (size_t)sIdx * 8;
#pragma unroll
        for (int j = 0; j < 8; ++j)
            dp[j] = (__bf16)ldf(W, (size_t)(krow + j) * DDIM + col, f);
    }
}

template <bool RESIDUAL>
__global__ __launch_bounds__(256) void mlp_kernel(
    const void* __restrict__ feat, const float* __restrict__ agg,
    const void* __restrict__ W1, const void* __restrict__ b1,
    const void* __restrict__ W2, const void* __restrict__ b2,
    const void* __restrict__ epsp, float* __restrict__ out, int N,
    const int* __restrict__ flags,
    int fiFeat, int fiW1, int fiB1, int fiW2, int fiB2, int fiEps)
{
    __shared__ alignas(16) __bf16 wf[32 * 64 * 8];
    __shared__ alignas(16) __bf16 h1t[64 * 136];

    const bool fF  = flags[fiFeat] != 0;
    const bool fB1 = flags[fiB1] != 0;
    const bool fB2 = flags[fiB2] != 0;
    const bool fE  = flags[fiEps] != 0;

    const int tid  = threadIdx.x;
    const int lane = tid & 63;
    const int wave = tid >> 6;
    const int quad = lane >> 4;
    const int r    = lane & 15;

    fill_wfrag(W1, flags[fiW1] != 0, wf, tid);

    const float eps1 = 1.f + ldf(epsp, 0, fE);
    const int rowBase = blockIdx.x * 64 + wave * 16;

    bf16x8 a[4];
    {
        int rowA = rowBase + r;
        if (rowA < N) {
            size_t fb = (size_t)rowA * DDIM + quad * 8;
            const f32x4* gp = (const f32x4*)(agg + fb);
            if (fF) {
                const f32x4* fp = (const f32x4*)((const float*)feat + fb);
#pragma unroll
                for (int kk = 0; kk < 4; ++kk) {
                    f32x4 f0 = fp[kk * 8], f1 = fp[kk * 8 + 1];
                    f32x4 g0 = gp[kk * 8], g1 = gp[kk * 8 + 1];
                    bf16x8 av;
#pragma unroll
                    for (int j = 0; j < 4; ++j) {
                        av[j]     = (__bf16)(f0[j] * eps1 + g0[j]);
                        av[j + 4] = (__bf16)(f1[j] * eps1 + g1[j]);
                    }
                    a[kk] = av;
                }
            } else {
                const bf16x8* fp = (const bf16x8*)((const bf16_t*)feat + fb);
#pragma unroll
                for (int kk = 0; kk < 4; ++kk) {
                    bf16x8 fv = fp[kk * 4];
                    f32x4 g0 = gp[kk * 8], g1 = gp[kk * 8 + 1];
                    bf16x8 av;
#pragma unroll
                    for (int j = 0; j < 4; ++j) {
                        av[j]     = (__bf16)((float)fv[j]     * eps1 + g0[j]);
                        av[j + 4] = (__bf16)((float)fv[j + 4] * eps1 + g1[j]);
                    }
                    a[kk] = av;
                }
            }
        } else {
#pragma unroll
            for (int kk = 0; kk < 4; ++kk)
#pragma unroll
                for (int j = 0; j < 8; ++j) a[kk][j] = (__bf16)0.f;
        }
    }

    __syncthreads();

    const bf16x8* wv = (const bf16x8*)wf;
#pragma unroll
    for (int ct = 0; ct < 8; ++ct) {
        f32x4 acc = {0.f, 0.f, 0.f, 0.f};
#pragma unroll
        for (int kk = 0; kk < 4; ++kk)
            acc = __builtin_amdgcn_mfma_f32_16x16x32_bf16(
                a[kk], wv[(ct * 4 + kk) * 64 + lane], acc, 0, 0, 0);
        float bias = ldf(b1, ct * 16 + r, fB1);
#pragma unroll
        for (int gg = 0; gg < 4; ++gg)
            h1t[(wave * 16 + quad * 4 + gg) * 136 + ct * 16 + r] =
                (__bf16)lrelu(acc[gg] + bias);
    }
    __syncthreads();

    bf16x8 a2[4];
#pragma unroll
    for (int kk = 0; kk < 4; ++kk)
        a2[kk] = *(const bf16x8*)&h1t[(wave * 16 + r) * 136 + kk * 32 + quad * 8];

    fill_wfrag(W2, flags[fiW2] != 0, wf, tid);
    __syncthreads();

#pragma unroll
    for (int ct = 0; ct < 8; ++ct) {
        f32x4 acc = {0.f, 0.f, 0.f, 0.f};
#pragma unroll
        for (int kk = 0; kk < 4; ++kk)
            acc = __builtin_amdgcn_mfma_f32_16x16x32_bf16(
                a2[kk], wv[(ct * 4 + kk) * 64 + lane], acc, 0, 0, 0);
        float bias = ldf(b2, ct * 16 + r, fB2);
#pragma unroll
        for (int gg = 0; gg < 4; ++gg) {
            int row = rowBase + quad * 4 + gg;
            if (row < N) {
                int col = ct * 16 + r;
                float v = lrelu(acc[gg] + bias);
                if (RESIDUAL) v += ldf(feat, (size_t)row * DDIM + col, fF);
                out[(size_t)row * DDIM + col] = v;
            }
        }
    }
}

extern "C" void kernel_launch(void* const* d_in, const int* in_sizes, int n_in,
                              void* d_out, int out_size, void* d_ws, size_t ws_size,
                              hipStream_t stream)
{
    const int* src_c2r = (const int*)d_in[2];
    const int* dst_c2r = (const int*)d_in[3];
    const int* src_r2c = (const int*)d_in[5];
    const int* dst_r2c = (const int*)d_in[6];
    const int nE = in_sizes[2];

    char* wsb = (char*)d_ws;
    int*    flags  = (int*)wsb;
    __bf16* wfprep = (__bf16*)(wsb + 128);

    // ---- A4 layout: cntA|ovCntA|cntB|ovCntB|slotsA|slotsB|ovLA|ovLB|cbufX|cbufH
    int*    cntA   = (int*)(wsb + 128 + 131072);
    int*    ovCntA = cntA + NROW;
    int*    cntB   = cntA + NROW + 8;
    int*    ovCntB = cntA + 2 * NROW + 8;
    size_t  o4 = 128 + 131072 + ((size_t)2 * NROW + 16) * 4;
    o4 = (o4 + 15) & ~(size_t)15;
    int*    slotsA = (int*)(wsb + o4);  o4 += (size_t)NROW * CAP * 4;
    int*    slotsB = (int*)(wsb + o4);  o4 += (size_t)NROW * CAP * 4;
    int*    ovLA   = (int*)(wsb + o4);  o4 += (size_t)nE * 4;
    int*    ovLB   = (int*)(wsb + o4);  o4 += (size_t)nE * 4;
    o4 = (o4 + 15) & ~(size_t)15;
    __bf16* cbX  = (__bf16*)(wsb + o4); o4 += (size_t)NCOL * DDIM * 2;
    __bf16* cbH  = (__bf16*)(wsb + o4); o4 += (size_t)NROW * DDIM * 2;
    const size_t NEED_A4 = o4;

    // ---- A2 (round-7) layout: cntA|ovCntA|cntB|ovCntB|slots2|ovLA|ovLB|cbuf
    size_t  ofsA2   = 128 + 131072 + ((size_t)2 * NROW + 16) * 4;
    ofsA2 = (ofsA2 + 15) & ~(size_t)15;
    int2*   slots2A2  = (int2*)(wsb + ofsA2);
    size_t  ofsOvA2   = ofsA2 + (size_t)NROW * CAP * 8;
    int*    ovListA2  = (int*)(wsb + ofsOvA2);
    int*    ovListB2  = ovListA2 + nE;
    size_t  ofsCbA2   = (ofsOvA2 + (size_t)nE * 8 + 15) & ~(size_t)15;
    __bf16* cbufA2    = (__bf16*)(wsb + ofsCbA2);
    const size_t NEED_A2 = ofsCbA2 + (size_t)NROW * DDIM * 2;

    const bool tierA4 = ws_size >= NEED_A4;
    const bool tierA2 = ws_size >= NEED_A2;

    TensorTab T;
    for (int i = 0; i < 18; ++i) { T.p[i] = d_in[i]; T.n[i] = in_sizes[i]; }

    float* out_row = (float*)d_out;
    float* out_col = out_row + (size_t)NROW * DDIM;
    const size_t aggBytes = (size_t)NROW * DDIM * sizeof(float);

    const int eblocks  = (nE + 255) / 256;
    const int sblocks  = (nE * 32 + 255) / 256;
    const int mblocksR = (NROW + 63) / 64;
    const int mblocksC = (NCOL + 63) / 64;
    const int csR      = (NROW + 15) / 16;
    const int csC      = (NCOL + 15) / 16;
    const int gblocksR = (NROW + 3) / 4;
    const int gblocksC = (NCOL + 3) / 4;
    const int cblocks  = (NCOL * DDIM / 8 + 255) / 256;
    const int zn2      = 2 * NROW + 16;
    const int zb2      = (zn2 + 255) / 256;

    WPtrs P;
    P.W[0] = d_in[8];  P.fi[0] = 8;
    P.W[1] = d_in[10]; P.fi[1] = 10;
    P.W[2] = d_in[12]; P.fi[2] = 12;
    P.W[3] = d_in[14]; P.fi[3] = 14;

    if (tierA4) {
        const int n8  = NCOL * DDIM / 8;              // 800000
        const int cb4 = (n8 + 1023) / 1024;           // convert blocks (1024t)
        const int eb4 = (nE + 1023) / 1024;           // fill blocks (1024t)
        // D1: detect dtypes || zero cntA/ovCntA/cntB/ovCntB
        detect_zero<<<18 + zb2, 256, 0, stream>>>(T, flags, cntA, zn2);
        // D2: convert cbufX || fillA, interleaved 4:3; weight prep at tail
        {
            int ka = (cb4 + 3) / 4, kb = (eb4 + 2) / 3;
            int K = ka > kb ? ka : kb;
            prep_fill_i2<<<7 * K + 8, 1024, 0, stream>>>(
                P, flags, wfprep, d_in[1], cbX, n8, 1, cb4, eb4, 7 * K,
                dst_c2r, nE, cntA, slotsA, ovCntA, ovLA);
        }
        // D3: fused segsumA + mlp1 (out_row = h+feat, cbufH = h bf16)
        //     || fillB, interleaved 4:3
        {
            int ka = (csR + 3) / 4, kb = (eb4 + 2) / 3;
            int K = ka > kb ? ka : kb;
            mlp_fused2<true, true><<<7 * K, 1024, 0, stream>>>(
                cbX, cntA, slotsA, src_c2r, dst_c2r, d_in[4], ovLA, ovCntA, 4,
                d_in[0], d_in[9], d_in[11], d_in[16],
                out_row, NROW, flags, 0, 9, 11, 16,
                wfprep + 0 * 16384, wfprep + 1 * 16384, cbH,
                csR, eb4, dst_r2c, nE, cntB, slotsB, ovCntB, ovLB);
        }
        // D4: fused segsumB + mlp2 -> out_col
        mlp_fused2<true, false><<<csC, 1024, 0, stream>>>(
            cbH, cntB, slotsB, src_r2c, dst_r2c, d_in[7], ovLB, ovCntB, 7,
            d_in[1], d_in[13], d_in[15], d_in[17],
            out_col, NCOL, flags, 1, 13, 15, 17,
            wfprep + 2 * 16384, wfprep + 3 * 16384, nullptr,
            csC, 0, nullptr, 0, nullptr, nullptr, nullptr, nullptr);
    } else if (tierA2) {
        // round-7 proven path
        detect_zero<<<18 + zb2, 256, 0, stream>>>(T, flags, cntA, zn2);
        prep_fill<<<cblocks + 32 + eblocks, 256, 0, stream>>>(
            P, flags, wfprep, d_in[1], cbufA2, NCOL * DDIM / 8, 1, cblocks,
            dst_c2r, src_c2r, d_in[4], nE, cntA, slots2A2, ovCntA,
            ovListA2, 4);
        segsum_scan<<<gblocksR, 256, 0, stream>>>(cbufA2, cntA, slots2A2,
            out_col, NROW, src_c2r, dst_c2r, d_in[4], ovListA2, ovCntA,
            flags, 4);
        mlp_cs<true, true><<<csR + eblocks, 256, 0, stream>>>(
            d_in[0], out_col, d_in[9], d_in[11], d_in[16],
            out_row, NROW, flags, 0, 9, 11, 16,
            wfprep + 0 * 16384, wfprep + 1 * 16384, cbufA2,
            csR, dst_r2c, src_r2c, d_in[7], nE, cntB, slots2A2,
            ovCntB, ovListB2, 7);
        segsum_scan<<<gblocksC, 256, 0, stream>>>(cbufA2, cntB, slots2A2,
            out_col, NCOL, src_r2c, dst_r2c, d_in[7], ovListB2, ovCntB,
            flags, 7);
        mlp_cs<true, false><<<csC, 256, 0, stream>>>(
            d_in[1], out_col, d_in[13], d_in[15], d_in[17],
            out_col, NCOL, flags, 1, 13, 15, 17,
            wfprep + 2 * 16384, wfprep + 3 * 16384, nullptr,
            csC, nullptr, nullptr, nullptr, 0, nullptr, nullptr,
            nullptr, nullptr, 0);
    } else {
        // legacy path
        detect_zero<<<18, 256, 0, stream>>>(T, flags, nullptr, 0);
        hipMemsetAsync(out_col, 0, aggBytes, stream);
        scatter_any<<<sblocks, 256, 0, stream>>>(d_in[1], src_c2r, dst_c2r,
            d_in[4], out_col, nE, flags, 1, 4);
        mlp_kernel<false><<<mblocksR, 256, 0, stream>>>(
            d_in[0], out_col, d_in[8], d_in[9], d_in[10], d_in[11], d_in[16],
            out_row, NROW, flags, 0, 8, 9, 10, 11, 16);

        hipMemsetAsync(out_col, 0, aggBytes, stream);
        scatter_any<<<sblocks, 256, 0, stream>>>(out_row, src_r2c, dst_r2c,
            d_in[7], out_col, nE, flags, -1, 7);
        residual_add<<<(NROW * DDIM / 4 + 255) / 256, 256, 0, stream>>>(
            out_row, d_in[0], NROW * DDIM / 4, flags, 0);
        mlp_kernel<true><<<mblocksC, 256, 0, stream>>>(
            d_in[1], out_col, d_in[12], d_in[13], d_in[14], d_in[15], d_in[17],
            out_col, NCOL, flags, 1, 12, 13, 14, 15, 17);
    }
}

// Round 10
// 306.233 us; speedup vs baseline: 1.0463x; 1.0463x over previous
//
#include <hip/hip_runtime.h>
#include <hip/hip_bf16.h>

#define NROW 50000
#define NCOL 50000
#define DDIM 128
#define CAP  32   // slots per destination row

typedef __bf16 bf16_t;
typedef __bf16 bf16x2 __attribute__((ext_vector_type(2)));
typedef __bf16 bf16x8 __attribute__((ext_vector_type(8)));
typedef float  f32x4  __attribute__((ext_vector_type(4)));

__device__ __forceinline__ float lrelu(float v) { return v >= 0.f ? v : 0.01f * v; }

__device__ __forceinline__ float ldf(const void* p, size_t i, bool f) {
    return f ? ((const float*)p)[i] : (float)((const bf16_t*)p)[i];
}

// fi: >=0 -> flags[fi]; -1 -> forced f32; -2 -> forced bf16
__device__ __forceinline__ bool dtf(const int* flags, int fi) {
    return (fi == -1) ? true : (fi == -2) ? false : (flags[fi] != 0);
}

// ---------------- D1: dtype detect (18 blocks) + zero counts ---------------
struct TensorTab { const void* p[18]; int n[18]; };

__global__ __launch_bounds__(256) void detect_zero(TensorTab T, int* flags,
                                                   int* z, int zn)
{
    const int tid = threadIdx.x;
    if (blockIdx.x >= 18) {                  // zero countsA|ovCntA|countsB|ovCntB
        int i = (blockIdx.x - 18) * 256 + tid;
        if (i < zn) z[i] = 0;
        return;
    }
    __shared__ int vb, vf;
    const int t = blockIdx.x;
    if (tid == 0) { vb = 0; vf = 0; }
    __syncthreads();
    const int n = T.n[t];
    const bool isFloatArr = (t != 2 && t != 3 && t != 5 && t != 6) && n >= 2;
    if (isFloatArr) {
        int nw = n / 2;
        int wi = (int)(((long long)tid * nw) >> 8);
        unsigned w = ((const unsigned*)T.p[t])[wi];
        unsigned low = w & 0xffffu;
        if (low) {
            int e = (int)((low >> 7) & 0xffu);
            if (e >= 90 && e <= 141) atomicAdd(&vb, 1);
            else                     atomicAdd(&vf, 1);
        }
    }
    __syncthreads();
    if (tid == 0) flags[t] = (isFloatArr && vf > vb) ? 1 : 0; // 1 = f32
}

// ---------------- fill: packed (src,w) int2 slots ---------------------------
// (proven round 3: gather reads become ONE coalesced 8B lane load per row;
// 4B edge-id variant measured +52MB fetch in round 9 -> reverted)
__device__ __forceinline__ void fill_edges(
    int e, const int* __restrict__ dst, const int* __restrict__ srcArr,
    const void* __restrict__ wArr, int nE, int* __restrict__ counts,
    int2* __restrict__ slots2, int* __restrict__ ovCnt,
    int* __restrict__ ovList, bool fW)
{
    if (e >= nE) return;
    int d = dst[e];
    int pos = atomicAdd(&counts[d], 1);
    if (pos < CAP) {
        int2 pk;
        pk.x = srcArr[e];
        pk.y = __float_as_int(ldf(wArr, e, fW));
        slots2[(size_t)d * CAP + pos] = pk;
    } else {
        int k = atomicAdd(ovCnt, 1);         // capacity == nE
        ovList[k] = e;
    }
}

struct WPtrs { const void* W[4]; int fi[4]; };

__device__ __forceinline__ void prep_one(WPtrs P, const int* flags,
                                         __bf16* wfp, int slot)
{
    if (slot >= 4 * 2048) return;
    int m = slot >> 11, sIdx = slot & 2047;
    bool f = flags[P.fi[m]] != 0;
    int l = sIdx & 63, combo = sIdx >> 6;
    int ct = combo >> 2, kk = combo & 3;
    int col  = ct * 16 + (l & 15);
    int krow = kk * 32 + (l >> 4) * 8;
    bf16x8 v;
#pragma unroll
    for (int j = 0; j < 8; ++j)
        v[j] = (__bf16)ldf(P.W[m], (size_t)(krow + j) * DDIM + col, f);
    ((bf16x8*)wfp)[slot] = v;
}

__device__ __forceinline__ void convert_one(const void* __restrict__ feat,
                                            __bf16* __restrict__ cbuf,
                                            int i, int n8, bool f)
{
    if (i >= n8) return;
    bf16x8 v;
    if (f) {
        f32x4 a = ((const f32x4*)feat)[i * 2];
        f32x4 c = ((const f32x4*)feat)[i * 2 + 1];
#pragma unroll
        for (int j = 0; j < 4; ++j) { v[j] = (__bf16)a[j]; v[j + 4] = (__bf16)c[j]; }
    } else {
        v = ((const bf16x8*)feat)[i];
    }
    ((bf16x8*)cbuf)[i] = v;
}

// ---------------- D2 (A5): convert || fillA interleaved 4:3, prep tail ------
__global__ __launch_bounds__(1024) void prep_fill_i2(
    WPtrs P, const int* __restrict__ flags, __bf16* __restrict__ wfp,
    const void* __restrict__ feat, __bf16* __restrict__ cbuf, int n8,
    int fiFeat, int cb, int eb, int K7,
    const int* __restrict__ f_dst, const int* __restrict__ f_src,
    const void* __restrict__ f_w, int f_nE, int* __restrict__ f_counts,
    int2* __restrict__ f_slots2, int* __restrict__ f_ovCnt,
    int* __restrict__ f_ovList, int f_fiW)
{
    const int g = blockIdx.x;
    const int tid = threadIdx.x;
    if (g >= K7) {                            // weight B-frag prep
        prep_one(P, flags, wfp, (g - K7) * 1024 + tid);
        return;
    }
    int grp = g / 7, rem = g % 7;
    if (rem < 4) {                            // convert feat table to bf16
        int b = grp * 4 + rem;
        if (b >= cb) return;
        convert_one(feat, cbuf, b * 1024 + tid, n8, dtf(flags, fiFeat));
    } else {                                  // fill stage-1 buckets
        int b = grp * 3 + (rem - 4);
        if (b >= eb) return;
        fill_edges(b * 1024 + tid, f_dst, f_src, f_w, f_nE, f_counts,
                   f_slots2, f_ovCnt, f_ovList, dtf(flags, f_fiW));
    }
}

// ---------------- A5: fused segsum + MLP, 16-wave blocks, packed slots ------
// Block = 1024 threads = 16 waves, 16 rows. Phase S: ONE ROW PER WAVE (r9's
// proven +0.5 TB/s structure) with PACKED int2 slots (r8's proven -52MB fetch:
// one coalesced 8B lane load per row, no srcArr/wArr indirection).
// MLP: waves 0-7 each own one 16-col tile (4+4 weight frags register-resident).
// fill role (interleaved 4:3): packed bucket-fill for the NEXT stage.
template <bool RESIDUAL, bool HOUT>
__global__ __launch_bounds__(1024) void mlp_fused2(
    const __bf16* __restrict__ gsrc, const int* __restrict__ counts,
    const int2* __restrict__ slots2, const int* __restrict__ srcArr,
    const int* __restrict__ dstArr, const void* __restrict__ wArr,
    const int* __restrict__ ovList, const int* __restrict__ ovCount, int fiW,
    const void* __restrict__ feat, const void* __restrict__ b1,
    const void* __restrict__ b2, const void* __restrict__ epsp,
    float* __restrict__ out, int N, const int* __restrict__ flags,
    int fiFeat, int fiB1, int fiB2, int fiEps,
    const __bf16* __restrict__ pW1, const __bf16* __restrict__ pW2,
    __bf16* __restrict__ hout,
    int mlpBlocks, int fillBlocks,
    const int* __restrict__ f_dst, const int* __restrict__ f_src,
    const void* __restrict__ f_w, int f_nE, int* __restrict__ f_counts,
    int2* __restrict__ f_slots2, int* __restrict__ f_ovCnt,
    int* __restrict__ f_ovList, int f_fiW)
{
    __shared__ alignas(16) __bf16 At[16 * 136];   // A tile (later: hout stage)
    __shared__ alignas(16) __bf16 H1[16 * 136];   // h1 exchange tile

    const int tid = threadIdx.x;
    int bid;
    if (f_dst) {                              // interleaved roles, 4 mlp : 3 fill
        int grp = (int)blockIdx.x / 7, rem = (int)blockIdx.x % 7;
        if (rem >= 4) {
            int b = grp * 3 + (rem - 4);
            if (b < fillBlocks)
                fill_edges(b * 1024 + tid, f_dst, f_src, f_w, f_nE, f_counts,
                           f_slots2, f_ovCnt, f_ovList, dtf(flags, f_fiW));
            return;
        }
        bid = grp * 4 + rem;
        if (bid >= mlpBlocks) return;
    } else {
        bid = blockIdx.x;
        if (bid >= mlpBlocks) return;
    }

    const bool fF  = flags[fiFeat] != 0;
    const bool fB1 = flags[fiB1] != 0;
    const bool fB2 = flags[fiB2] != 0;
    const bool fE  = flags[fiEps] != 0;

    const int lane = tid & 63;
    const int wave = tid >> 6;                // 0..15
    const int quad = lane >> 4;
    const int r    = lane & 15;
    const int rowBase = bid * 16;
    const float eps1 = 1.f + ldf(epsp, 0, fE);

    // ---- Phase S: gather, ONE row per wave, packed slots (4-deep pipeline) -
    {
        const bf16x2* fb = (const bf16x2*)gsrc;
        int row = rowBase + wave;
        bf16x2 o;
        if (row < N) {
            int cntRaw = counts[row];
            int cnt = cntRaw > CAP ? CAP : cntRaw;
            int sr = 0; float wv = 0.f;
            if (lane < cnt) {                 // one coalesced 8B lane load
                int2 pk = slots2[(size_t)row * CAP + lane];
                sr = pk.x;
                wv = __int_as_float(pk.y);
            }
            float2 acc0 = {0.f, 0.f}, acc1 = {0.f, 0.f};
            int i = 0;
            for (; i + 4 <= cnt; i += 4) {
                int   a0 = __shfl(sr, i),     a1 = __shfl(sr, i + 1);
                int   a2 = __shfl(sr, i + 2), a3 = __shfl(sr, i + 3);
                float w0 = __shfl(wv, i),     w1 = __shfl(wv, i + 1);
                float w2 = __shfl(wv, i + 2), w3 = __shfl(wv, i + 3);
                bf16x2 v0 = fb[(size_t)a0 * 64 + lane];
                bf16x2 v1 = fb[(size_t)a1 * 64 + lane];
                bf16x2 v2 = fb[(size_t)a2 * 64 + lane];
                bf16x2 v3 = fb[(size_t)a3 * 64 + lane];
                acc0.x += (float)v0[0] * w0; acc0.y += (float)v0[1] * w0;
                acc1.x += (float)v1[0] * w1; acc1.y += (float)v1[1] * w1;
                acc0.x += (float)v2[0] * w2; acc0.y += (float)v2[1] * w2;
                acc1.x += (float)v3[0] * w3; acc1.y += (float)v3[1] * w3;
            }
            for (; i < cnt; ++i) {
                int   a0 = __shfl(sr, i);
                float w0 = __shfl(wv, i);
                bf16x2 v0 = fb[(size_t)a0 * 64 + lane];
                acc0.x += (float)v0[0] * w0; acc0.y += (float)v0[1] * w0;
            }
            if (cntRaw > CAP) {               // rare: exact overflow scan
                const bool fW = dtf(flags, fiW);
                int nOv = *ovCount;
                for (int k = 0; k < nOv; ++k) {
                    int e = ovList[k];
                    if (dstArr[e] == row) {
                        int s = srcArr[e];
                        float wf = ldf(wArr, e, fW);
                        bf16x2 v = fb[(size_t)s * 64 + lane];
                        acc0.x += (float)v[0] * wf;
                        acc0.y += (float)v[1] * wf;
                    }
                }
            }
            float ax = acc0.x + acc1.x, ay = acc0.y + acc1.y;
            float f0, f1;
            if (fF) {
                float2 fv = ((const float2*)((const float*)feat +
                             (size_t)row * DDIM))[lane];
                f0 = fv.x; f1 = fv.y;
            } else {
                bf16x2 fv = ((const bf16x2*)((const bf16_t*)feat +
                             (size_t)row * DDIM))[lane];
                f0 = (float)fv[0]; f1 = (float)fv[1];
            }
            o[0] = (__bf16)(f0 * eps1 + ax);
            o[1] = (__bf16)(f1 * eps1 + ay);
        } else {
            o[0] = (__bf16)0.f; o[1] = (__bf16)0.f;
        }
        *(bf16x2*)&At[wave * 136 + lane * 2] = o;
    }
    __syncthreads();

    // ---- layer 1: waves 0-7, one 16-col tile each ----
    const int ct = wave;
    if (wave < 8) {
        bf16x8 a[4];
#pragma unroll
        for (int kk = 0; kk < 4; ++kk)
            a[kk] = *(const bf16x8*)&At[r * 136 + kk * 32 + quad * 8];
        const bf16x8* pw1v = (const bf16x8*)pW1;
        bf16x8 w1f[4];
#pragma unroll
        for (int kk = 0; kk < 4; ++kk)
            w1f[kk] = pw1v[(ct * 4 + kk) * 64 + lane];
        float b1v = ldf(b1, ct * 16 + r, fB1);
        f32x4 acc = {0.f, 0.f, 0.f, 0.f};
#pragma unroll
        for (int kk = 0; kk < 4; ++kk)
            acc = __builtin_amdgcn_mfma_f32_16x16x32_bf16(a[kk], w1f[kk], acc, 0, 0, 0);
#pragma unroll
        for (int gg = 0; gg < 4; ++gg)
            H1[(quad * 4 + gg) * 136 + ct * 16 + r] = (__bf16)lrelu(acc[gg] + b1v);
    }
    __syncthreads();

    // ---- layer 2: waves 0-7 -> out (+residual); HOUT: stage bf16 h in At ---
    if (wave < 8) {
        bf16x8 a2[4];
#pragma unroll
        for (int kk = 0; kk < 4; ++kk)
            a2[kk] = *(const bf16x8*)&H1[r * 136 + kk * 32 + quad * 8];
        const bf16x8* pw2v = (const bf16x8*)pW2;
        bf16x8 w2f[4];
#pragma unroll
        for (int kk = 0; kk < 4; ++kk)
            w2f[kk] = pw2v[(ct * 4 + kk) * 64 + lane];
        float b2v = ldf(b2, ct * 16 + r, fB2);
        f32x4 acc = {0.f, 0.f, 0.f, 0.f};
#pragma unroll
        for (int kk = 0; kk < 4; ++kk)
            acc = __builtin_amdgcn_mfma_f32_16x16x32_bf16(a2[kk], w2f[kk], acc, 0, 0, 0);
#pragma unroll
        for (int gg = 0; gg < 4; ++gg) {
            int row = rowBase + quad * 4 + gg;
            float v = lrelu(acc[gg] + b2v);
            if (HOUT)
                At[(quad * 4 + gg) * 136 + ct * 16 + r] = (__bf16)v;
            if (row < N) {
                int col = ct * 16 + r;
                if (RESIDUAL) v += ldf(feat, (size_t)row * DDIM + col, fF);
                out[(size_t)row * DDIM + col] = v;
            }
        }
    }

    // ---- cooperative coalesced hout store ----
    if (HOUT) {
        __syncthreads();
        if (tid < 256) {                      // 16 rows x 16 chunks of bf16x8
            int row = tid >> 4;
            int k0  = (tid & 15) * 8;
            int g   = rowBase + row;
            if (g < N)
                *(bf16x8*)&hout[(size_t)g * DDIM + k0] =
                    *(const bf16x8*)&At[row * 136 + k0];
        }
    }
}

// =================== round-7 tier-A2 fallback kernels (proven) ==============
__global__ __launch_bounds__(256) void prep_fill(
    WPtrs P, const int* __restrict__ flags, __bf16* __restrict__ wfp,
    const void* __restrict__ feat, __bf16* __restrict__ cbuf, int n8,
    int fiFeat, int cblocks,
    const int* __restrict__ f_dst, const int* __restrict__ f_src,
    const void* __restrict__ f_w, int f_nE, int* __restrict__ f_counts,
    int2* __restrict__ f_slots2, int* __restrict__ f_ovCnt,
    int* __restrict__ f_ovList, int f_fiW)
{
    const int b = blockIdx.x;
    const int tid = threadIdx.x;
    if (b < cblocks) {
        convert_one(feat, cbuf, b * 256 + tid, n8, dtf(flags, fiFeat));
    } else if (b < cblocks + 32) {
        prep_one(P, flags, wfp, (b - cblocks) * 256 + tid);
    } else {
        int e = (b - cblocks - 32) * 256 + tid;
        fill_edges(e, f_dst, f_src, f_w, f_nE, f_counts, f_slots2,
                   f_ovCnt, f_ovList, dtf(flags, f_fiW));
    }
}

__global__ __launch_bounds__(256) void segsum_scan(
    const __bf16* __restrict__ gsrc, const int* __restrict__ counts,
    const int2* __restrict__ slots2, float* __restrict__ agg, int nRows,
    const int* __restrict__ srcArr, const int* __restrict__ dstArr,
    const void* __restrict__ wArr, const int* __restrict__ ovList,
    const int* __restrict__ ovCount, const int* __restrict__ flags, int fiW)
{
    int row = blockIdx.x * 4 + (threadIdx.x >> 6);
    if (row >= nRows) return;
    int lane = threadIdx.x & 63;

    int cntRaw = counts[row];
    int cnt = cntRaw > CAP ? CAP : cntRaw;

    int sr = 0; float wv = 0.f;
    if (lane < cnt) {
        int2 pk = slots2[(size_t)row * CAP + lane];
        sr = pk.x;
        wv = __int_as_float(pk.y);
    }

    float2* ap = (float2*)(agg + (size_t)row * DDIM) + lane;
    float2 acc0 = {0.f, 0.f}, acc1 = {0.f, 0.f};

    const bf16x2* fb = (const bf16x2*)gsrc;
    int i = 0;
    for (; i + 4 <= cnt; i += 4) {
        int   a0 = __shfl(sr, i),     a1 = __shfl(sr, i + 1);
        int   a2 = __shfl(sr, i + 2), a3 = __shfl(sr, i + 3);
        float w0 = __shfl(wv, i),     w1 = __shfl(wv, i + 1);
        float w2 = __shfl(wv, i + 2), w3 = __shfl(wv, i + 3);
        bf16x2 v0 = fb[(size_t)a0 * 64 + lane];
        bf16x2 v1 = fb[(size_t)a1 * 64 + lane];
        bf16x2 v2 = fb[(size_t)a2 * 64 + lane];
        bf16x2 v3 = fb[(size_t)a3 * 64 + lane];
        acc0.x += (float)v0[0] * w0; acc0.y += (float)v0[1] * w0;
        acc1.x += (float)v1[0] * w1; acc1.y += (float)v1[1] * w1;
        acc0.x += (float)v2[0] * w2; acc0.y += (float)v2[1] * w2;
        acc1.x += (float)v3[0] * w3; acc1.y += (float)v3[1] * w3;
    }
    for (; i < cnt; ++i) {
        int   a0 = __shfl(sr, i);
        float w0 = __shfl(wv, i);
        bf16x2 v0 = fb[(size_t)a0 * 64 + lane];
        acc0.x += (float)v0[0] * w0; acc0.y += (float)v0[1] * w0;
    }
    if (cntRaw > CAP) {
        const bool fW = dtf(flags, fiW);
        int nOv = *ovCount;
        for (int k = 0; k < nOv; ++k) {
            int e = ovList[k];
            if (dstArr[e] == row) {
                int s = srcArr[e];
                float wf = ldf(wArr, e, fW);
                bf16x2 v = fb[(size_t)s * 64 + lane];
                acc0.x += (float)v[0] * wf; acc0.y += (float)v[1] * wf;
            }
        }
    }
    acc0.x += acc1.x; acc0.y += acc1.y;
    *ap = acc0;
}

template <bool RESIDUAL, bool HOUT>
__global__ __launch_bounds__(256) void mlp_cs(
    const void* __restrict__ feat, const float* __restrict__ agg,
    const void* __restrict__ b1, const void* __restrict__ b2,
    const void* __restrict__ epsp, float* __restrict__ out, int N,
    const int* __restrict__ flags, int fiFeat, int fiB1, int fiB2, int fiEps,
    const __bf16* __restrict__ pW1, const __bf16* __restrict__ pW2,
    __bf16* __restrict__ hout,
    int mblocks,
    const int* __restrict__ f_dst, const int* __restrict__ f_src,
    const void* __restrict__ f_w, int f_nE, int* __restrict__ f_counts,
    int2* __restrict__ f_slots2, int* __restrict__ f_ovCnt,
    int* __restrict__ f_ovList, int f_fiW)
{
    __shared__ alignas(16) __bf16 At[16 * 136];
    __shared__ alignas(16) __bf16 H1[16 * 136];

    const int tid = threadIdx.x;
    if (f_dst && (int)blockIdx.x >= mblocks) {
        int e = ((int)blockIdx.x - mblocks) * 256 + tid;
        fill_edges(e, f_dst, f_src, f_w, f_nE, f_counts, f_slots2,
                   f_ovCnt, f_ovList, dtf(flags, f_fiW));
        return;
    }

    const bool fF  = flags[fiFeat] != 0;
    const bool fB1 = flags[fiB1] != 0;
    const bool fB2 = flags[fiB2] != 0;
    const bool fE  = flags[fiEps] != 0;

    const int lane = tid & 63;
    const int wave = tid >> 6;
    const int quad = lane >> 4;
    const int r    = lane & 15;
    const int rowBase = blockIdx.x * 16;
    const float eps1 = 1.f + ldf(epsp, 0, fE);

    {
        int row = tid >> 4;
        int k0  = (tid & 15) * 8;
        int g   = rowBase + row;
        bf16x8 av;
        if (g < N) {
            size_t base = (size_t)g * DDIM + k0;
            const f32x4* gp = (const f32x4*)(agg + base);
            f32x4 g0 = gp[0], g1 = gp[1];
            if (fF) {
                const f32x4* fp = (const f32x4*)((const float*)feat + base);
                f32x4 f0 = fp[0], f1 = fp[1];
#pragma unroll
                for (int j = 0; j < 4; ++j) {
                    av[j]     = (__bf16)(f0[j] * eps1 + g0[j]);
                    av[j + 4] = (__bf16)(f1[j] * eps1 + g1[j]);
                }
            } else {
                bf16x8 fv = *(const bf16x8*)((const bf16_t*)feat + base);
#pragma unroll
                for (int j = 0; j < 4; ++j) {
                    av[j]     = (__bf16)((float)fv[j]     * eps1 + g0[j]);
                    av[j + 4] = (__bf16)((float)fv[j + 4] * eps1 + g1[j]);
                }
            }
        } else {
#pragma unroll
            for (int j = 0; j < 8; ++j) av[j] = (__bf16)0.f;
        }
        *(bf16x8*)&At[row * 136 + k0] = av;
    }
    __syncthreads();

    bf16x8 a[4];
#pragma unroll
    for (int kk = 0; kk < 4; ++kk)
        a[kk] = *(const bf16x8*)&At[r * 136 + kk * 32 + quad * 8];

    const int ct0 = wave * 2, ct1 = ct0 + 1;

    const bf16x8* pw1v = (const bf16x8*)pW1;
    bf16x8 wfa[4], wfb[4];
#pragma unroll
    for (int kk = 0; kk < 4; ++kk) {
        wfa[kk] = pw1v[(ct0 * 4 + kk) * 64 + lane];
        wfb[kk] = pw1v[(ct1 * 4 + kk) * 64 + lane];
    }
    float b1a = ldf(b1, ct0 * 16 + r, fB1);
    float b1b = ldf(b1, ct1 * 16 + r, fB1);

    {
        f32x4 acc = {0.f, 0.f, 0.f, 0.f};
#pragma unroll
        for (int kk = 0; kk < 4; ++kk)
            acc = __builtin_amdgcn_mfma_f32_16x16x32_bf16(a[kk], wfa[kk], acc, 0, 0, 0);
#pragma unroll
        for (int gg = 0; gg < 4; ++gg)
            H1[(quad * 4 + gg) * 136 + ct0 * 16 + r] = (__bf16)lrelu(acc[gg] + b1a);
    }
    {
        f32x4 acc = {0.f, 0.f, 0.f, 0.f};
#pragma unroll
        for (int kk = 0; kk < 4; ++kk)
            acc = __builtin_amdgcn_mfma_f32_16x16x32_bf16(a[kk], wfb[kk], acc, 0, 0, 0);
#pragma unroll
        for (int gg = 0; gg < 4; ++gg)
            H1[(quad * 4 + gg) * 136 + ct1 * 16 + r] = (__bf16)lrelu(acc[gg] + b1b);
    }
    __syncthreads();

    bf16x8 a2[4];
#pragma unroll
    for (int kk = 0; kk < 4; ++kk)
        a2[kk] = *(const bf16x8*)&H1[r * 136 + kk * 32 + quad * 8];

    const bf16x8* pw2v = (const bf16x8*)pW2;
#pragma unroll
    for (int kk = 0; kk < 4; ++kk) {
        wfa[kk] = pw2v[(ct0 * 4 + kk) * 64 + lane];
        wfb[kk] = pw2v[(ct1 * 4 + kk) * 64 + lane];
    }
    float b2a = ldf(b2, ct0 * 16 + r, fB2);
    float b2b = ldf(b2, ct1 * 16 + r, fB2);

#pragma unroll
    for (int cp = 0; cp < 2; ++cp) {
        const int ct = cp ? ct1 : ct0;
        f32x4 acc = {0.f, 0.f, 0.f, 0.f};
#pragma unroll
        for (int kk = 0; kk < 4; ++kk)
            acc = __builtin_amdgcn_mfma_f32_16x16x32_bf16(
                a2[kk], cp ? wfb[kk] : wfa[kk], acc, 0, 0, 0);
        float bias = cp ? b2b : b2a;
#pragma unroll
        for (int gg = 0; gg < 4; ++gg) {
            int row = rowBase + quad * 4 + gg;
            float v = lrelu(acc[gg] + bias);
            if (HOUT)
                At[(quad * 4 + gg) * 136 + ct * 16 + r] = (__bf16)v;
            if (row < N) {
                int col = ct * 16 + r;
                if (RESIDUAL) v += ldf(feat, (size_t)row * DDIM + col, fF);
                out[(size_t)row * DDIM + col] = v;
            }
        }
    }

    if (HOUT) {
        __syncthreads();
        int row = tid >> 4;
        int k0  = (tid & 15) * 8;
        int g   = rowBase + row;
        if (g < N)
            *(bf16x8*)&hout[(size_t)g * DDIM + k0] =
                *(const bf16x8*)&At[row * 136 + k0];
    }
}

// ======================= legacy kernels (ws-too-small) ======================
__global__ __launch_bounds__(256) void scatter_any(
    const void* __restrict__ feat, const int* __restrict__ src,
    const int* __restrict__ dst, const void* __restrict__ w,
    float* __restrict__ agg, int nE,
    const int* __restrict__ flags, int fiFeat, int fiW)
{
    const bool fF = dtf(flags, fiFeat);
    const bool fW = dtf(flags, fiW);
    int g = blockIdx.x * 256 + threadIdx.x;
    int e = g >> 5;
    if (e >= nE) return;
    int c = (g & 31) << 2;
    int s = src[e], d = dst[e];
    float wf = ldf(w, e, fW);
    size_t base = (size_t)s * DDIM + c;
    float* ap = agg + (size_t)d * DDIM + c;
    unsafeAtomicAdd(ap + 0, ldf(feat, base + 0, fF) * wf);
    unsafeAtomicAdd(ap + 1, ldf(feat, base + 1, fF) * wf);
    unsafeAtomicAdd(ap + 2, ldf(feat, base + 2, fF) * wf);
    unsafeAtomicAdd(ap + 3, ldf(feat, base + 3, fF) * wf);
}

__global__ __launch_bounds__(256) void residual_add(
    float* __restrict__ out, const void* __restrict__ feat, int n4,
    const int* __restrict__ flags, int fiFeat)
{
    const bool fF = flags[fiFeat] != 0;
    int i = blockIdx.x * 256 + threadIdx.x;
    if (i >= n4) return;
    f32x4 o = ((const f32x4*)out)[i];
    f32x4 r;
#pragma unroll
    for (int j = 0; j < 4; ++j) r[j] = o[j] + ldf(feat, (size_t)i * 4 + j, fF);
    ((f32x4*)out)[i] = r;
}

__device__ __forceinline__ void fill_wfrag(const void* __restrict__ W, bool f,
                                           __bf16* wf, int tid)
{
#pragma unroll
    for (int i = 0; i < 8; ++i) {
        int sIdx  = tid + i * 256;
        int l     = sIdx & 63;
        int combo = sIdx >> 6;
        int ct = combo >> 2, kk = combo & 3;
        int col  = ct * 16 + (l & 15);
        int krow = kk * 32 + (l >> 4) * 8;
        __bf16* dp = wf + (size_t)sIdx * 8;
#pragma unroll
        for (int j = 0; j < 8; ++j)
            dp[j] = (__bf16)ldf(W, (size_t)(krow + j) * DDIM + col, f);
    }
}

template <bool RESIDUAL>
__global__ __launch_bounds__(256) void mlp_kernel(
    const void* __restrict__ feat, const float* __restrict__ agg,
    const void* __restrict__ W1, const void* __restrict__ b1,
    const void* __restrict__ W2, const void* __restrict__ b2,
    const void* __restrict__ epsp, float* __restrict__ out, int N,
    const int* __restrict__ flags,
    int fiFeat, int fiW1, int fiB1, int fiW2, int fiB2, int fiEps)
{
    __shared__ alignas(16) __bf16 wf[32 * 64 * 8];
    __shared__ alignas(16) __bf16 h1t[64 * 136];

    const bool fF  = flags[fiFeat] != 0;
    const bool fB1 = flags[fiB1] != 0;
    const bool fB2 = flags[fiB2] != 0;
    const bool fE  = flags[fiEps] != 0;

    const int tid  = threadIdx.x;
    const int lane = tid & 63;
    const int wave = tid >> 6;
    const int quad = lane >> 4;
    const int r    = lane & 15;

    fill_wfrag(W1, flags[fiW1] != 0, wf, tid);

    const float eps1 = 1.f + ldf(epsp, 0, fE);
    const int rowBase = blockIdx.x * 64 + wave * 16;

    bf16x8 a[4];
    {
        int rowA = rowBase + r;
        if (rowA < N) {
            size_t fb = (size_t)rowA * DDIM + quad * 8;
            const f32x4* gp = (const f32x4*)(agg + fb);
            if (fF) {
                const f32x4* fp = (const f32x4*)((const float*)feat + fb);
#pragma unroll
                for (int kk = 0; kk < 4; ++kk) {
                    f32x4 f0 = fp[kk * 8], f1 = fp[kk * 8 + 1];
                    f32x4 g0 = gp[kk * 8], g1 = gp[kk * 8 + 1];
                    bf16x8 av;
#pragma unroll
                    for (int j = 0; j < 4; ++j) {
                        av[j]     = (__bf16)(f0[j] * eps1 + g0[j]);
                        av[j + 4] = (__bf16)(f1[j] * eps1 + g1[j]);
                    }
                    a[kk] = av;
                }
            } else {
                const bf16x8* fp = (const bf16x8*)((const bf16_t*)feat + fb);
#pragma unroll
                for (int kk = 0; kk < 4; ++kk) {
                    bf16x8 fv = fp[kk * 4];
                    f32x4 g0 = gp[kk * 8], g1 = gp[kk * 8 + 1];
                    bf16x8 av;
#pragma unroll
                    for (int j = 0; j < 4; ++j) {
                        av[j]     = (__bf16)((float)fv[j]     * eps1 + g0[j]);
                        av[j + 4] = (__bf16)((float)fv[j + 4] * eps1 + g1[j]);
                    }
                    a[kk] = av;
                }
            }
        } else {
#pragma unroll
            for (int kk = 0; kk < 4; ++kk)
#pragma unroll
                for (int j = 0; j < 8; ++j) a[kk][j] = (__bf16)0.f;
        }
    }

    __syncthreads();

    const bf16x8* wv = (const bf16x8*)wf;
#pragma unroll
    for (int ct = 0; ct < 8; ++ct) {
        f32x4 acc = {0.f, 0.f, 0.f, 0.f};
#pragma unroll
        for (int kk = 0; kk < 4; ++kk)
            acc = __builtin_amdgcn_mfma_f32_16x16x32_bf16(
                a[kk], wv[(ct * 4 + kk) * 64 + lane], acc, 0, 0, 0);
        float bias = ldf(b1, ct * 16 + r, fB1);
#pragma unroll
        for (int gg = 0; gg < 4; ++gg)
            h1t[(wave * 16 + quad * 4 + gg) * 136 + ct * 16 + r] =
                (__bf16)lrelu(acc[gg] + bias);
    }
    __syncthreads();

    bf16x8 a2[4];
#pragma unroll
    for (int kk = 0; kk < 4; ++kk)
        a2[kk] = *(const bf16x8*)&h1t[(wave * 16 + r) * 136 + kk * 32 + quad * 8];

    fill_wfrag(W2, flags[fiW2] != 0, wf, tid);
    __syncthreads();

#pragma unroll
    for (int ct = 0; ct < 8; ++ct) {
        f32x4 acc = {0.f, 0.f, 0.f, 0.f};
#pragma unroll
        for (int kk = 0; kk < 4; ++kk)
            acc = __builtin_amdgcn_mfma_f32_16x16x32_bf16(
                a2[kk], wv[(ct * 4 + kk) * 64 + lane], acc, 0, 0, 0);
        float bias = ldf(b2, ct * 16 + r, fB2);
#pragma unroll
        for (int gg = 0; gg < 4; ++gg) {
            int row = rowBase + quad * 4 + gg;
            if (row < N) {
                int col = ct * 16 + r;
                float v = lrelu(acc[gg] + bias);
                if (RESIDUAL) v += ldf(feat, (size_t)row * DDIM + col, fF);
                out[(size_t)row * DDIM + col] = v;
            }
        }
    }
}

extern "C" void kernel_launch(void* const* d_in, const int* in_sizes, int n_in,
                              void* d_out, int out_size, void* d_ws, size_t ws_size,
                              hipStream_t stream)
{
    const int* src_c2r = (const int*)d_in[2];
    const int* dst_c2r = (const int*)d_in[3];
    const int* src_r2c = (const int*)d_in[5];
    const int* dst_r2c = (const int*)d_in[6];
    const int nE = in_sizes[2];

    char* wsb = (char*)d_ws;
    int*    flags  = (int*)wsb;
    __bf16* wfprep = (__bf16*)(wsb + 128);

    // ---- A5 layout: cntA|ovCntA|cntB|ovCntB|slots2A|slots2B|ovLA|ovLB|cbufX|cbufH
    int*    cntA   = (int*)(wsb + 128 + 131072);
    int*    ovCntA = cntA + NROW;
    int*    cntB   = cntA + NROW + 8;
    int*    ovCntB = cntA + 2 * NROW + 8;
    size_t  o5 = 128 + 131072 + ((size_t)2 * NROW + 16) * 4;
    o5 = (o5 + 15) & ~(size_t)15;
    int2*   sl2A = (int2*)(wsb + o5);  o5 += (size_t)NROW * CAP * 8;
    int2*   sl2B = (int2*)(wsb + o5);  o5 += (size_t)NROW * CAP * 8;
    int*    ovLA = (int*)(wsb + o5);   o5 += (size_t)nE * 4;
    int*    ovLB = (int*)(wsb + o5);   o5 += (size_t)nE * 4;
    o5 = (o5 + 15) & ~(size_t)15;
    __bf16* cbX  = (__bf16*)(wsb + o5); o5 += (size_t)NCOL * DDIM * 2;
    __bf16* cbH  = (__bf16*)(wsb + o5); o5 += (size_t)NROW * DDIM * 2;
    const size_t NEED_A5 = o5;

    // ---- A2 (round-7) layout: cntA|ovCntA|cntB|ovCntB|slots2|ovLA|ovLB|cbuf
    size_t  ofsA2   = 128 + 131072 + ((size_t)2 * NROW + 16) * 4;
    ofsA2 = (ofsA2 + 15) & ~(size_t)15;
    int2*   slots2A2  = (int2*)(wsb + ofsA2);
    size_t  ofsOvA2   = ofsA2 + (size_t)NROW * CAP * 8;
    int*    ovListA2  = (int*)(wsb + ofsOvA2);
    int*    ovListB2  = ovListA2 + nE;
    size_t  ofsCbA2   = (ofsOvA2 + (size_t)nE * 8 + 15) & ~(size_t)15;
    __bf16* cbufA2    = (__bf16*)(wsb + ofsCbA2);
    const size_t NEED_A2 = ofsCbA2 + (size_t)NROW * DDIM * 2;

    const bool tierA5 = ws_size >= NEED_A5;
    const bool tierA2 = ws_size >= NEED_A2;

    TensorTab T;
    for (int i = 0; i < 18; ++i) { T.p[i] = d_in[i]; T.n[i] = in_sizes[i]; }

    float* out_row = (float*)d_out;
    float* out_col = out_row + (size_t)NROW * DDIM;
    const size_t aggBytes = (size_t)NROW * DDIM * sizeof(float);

    const int eblocks  = (nE + 255) / 256;
    const int sblocks  = (nE * 32 + 255) / 256;
    const int mblocksR = (NROW + 63) / 64;
    const int mblocksC = (NCOL + 63) / 64;
    const int csR      = (NROW + 15) / 16;
    const int csC      = (NCOL + 15) / 16;
    const int gblocksR = (NROW + 3) / 4;
    const int gblocksC = (NCOL + 3) / 4;
    const int cblocks  = (NCOL * DDIM / 8 + 255) / 256;
    const int zn2      = 2 * NROW + 16;
    const int zb2      = (zn2 + 255) / 256;

    WPtrs P;
    P.W[0] = d_in[8];  P.fi[0] = 8;
    P.W[1] = d_in[10]; P.fi[1] = 10;
    P.W[2] = d_in[12]; P.fi[2] = 12;
    P.W[3] = d_in[14]; P.fi[3] = 14;

    if (tierA5) {
        const int n8  = NCOL * DDIM / 8;              // 800000
        const int cb4 = (n8 + 1023) / 1024;           // convert blocks (1024t)
        const int eb4 = (nE + 1023) / 1024;           // fill blocks (1024t)
        // D1: detect dtypes || zero cntA/ovCntA/cntB/ovCntB
        detect_zero<<<18 + zb2, 256, 0, stream>>>(T, flags, cntA, zn2);
        // D2: convert cbufX || fillA (packed), interleaved 4:3; prep at tail
        {
            int ka = (cb4 + 3) / 4, kb = (eb4 + 2) / 3;
            int K = ka > kb ? ka : kb;
            prep_fill_i2<<<7 * K + 8, 1024, 0, stream>>>(
                P, flags, wfprep, d_in[1], cbX, n8, 1, cb4, eb4, 7 * K,
                dst_c2r, src_c2r, d_in[4], nE, cntA, sl2A, ovCntA, ovLA, 4);
        }
        // D3: fused segsumA + mlp1 (out_row = h+feat, cbufH = h bf16)
        //     || fillB (packed), interleaved 4:3
        {
            int ka = (csR + 3) / 4, kb = (eb4 + 2) / 3;
            int K = ka > kb ? ka : kb;
            mlp_fused2<true, true><<<7 * K, 1024, 0, stream>>>(
                cbX, cntA, sl2A, src_c2r, dst_c2r, d_in[4], ovLA, ovCntA, 4,
                d_in[0], d_in[9], d_in[11], d_in[16],
                out_row, NROW, flags, 0, 9, 11, 16,
                wfprep + 0 * 16384, wfprep + 1 * 16384, cbH,
                csR, eb4, dst_r2c, src_r2c, d_in[7], nE, cntB, sl2B,
                ovCntB, ovLB, 7);
        }
        // D4: fused segsumB + mlp2 -> out_col
        mlp_fused2<true, false><<<csC, 1024, 0, stream>>>(
            cbH, cntB, sl2B, src_r2c, dst_r2c, d_in[7], ovLB, ovCntB, 7,
            d_in[1], d_in[13], d_in[15], d_in[17],
            out_col, NCOL, flags, 1, 13, 15, 17,
            wfprep + 2 * 16384, wfprep + 3 * 16384, nullptr,
            csC, 0, nullptr, nullptr, nullptr, 0, nullptr, nullptr,
            nullptr, nullptr, 0);
    } else if (tierA2) {
        // round-7 proven path
        detect_zero<<<18 + zb2, 256, 0, stream>>>(T, flags, cntA, zn2);
        prep_fill<<<cblocks + 32 + eblocks, 256, 0, stream>>>(
            P, flags, wfprep, d_in[1], cbufA2, NCOL * DDIM / 8, 1, cblocks,
            dst_c2r, src_c2r, d_in[4], nE, cntA, slots2A2, ovCntA,
            ovListA2, 4);
        segsum_scan<<<gblocksR, 256, 0, stream>>>(cbufA2, cntA, slots2A2,
            out_col, NROW, src_c2r, dst_c2r, d_in[4], ovListA2, ovCntA,
            flags, 4);
        mlp_cs<true, true><<<csR + eblocks, 256, 0, stream>>>(
            d_in[0], out_col, d_in[9], d_in[11], d_in[16],
            out_row, NROW, flags, 0, 9, 11, 16,
            wfprep + 0 * 16384, wfprep + 1 * 16384, cbufA2,
            csR, dst_r2c, src_r2c, d_in[7], nE, cntB, slots2A2,
            ovCntB, ovListB2, 7);
        segsum_scan<<<gblocksC, 256, 0, stream>>>(cbufA2, cntB, slots2A2,
            out_col, NCOL, src_r2c, dst_r2c, d_in[7], ovListB2, ovCntB,
            flags, 7);
        mlp_cs<true, false><<<csC, 256, 0, stream>>>(
            d_in[1], out_col, d_in[13], d_in[15], d_in[17],
            out_col, NCOL, flags, 1, 13, 15, 17,
            wfprep + 2 * 16384, wfprep + 3 * 16384, nullptr,
            csC, nullptr, nullptr, nullptr, 0, nullptr, nullptr,
            nullptr, nullptr, 0);
    } else {
        // legacy path
        detect_zero<<<18, 256, 0, stream>>>(T, flags, nullptr, 0);
        hipMemsetAsync(out_col, 0, aggBytes, stream);
        scatter_any<<<sblocks, 256, 0, stream>>>(d_in[1], src_c2r, dst_c2r,
            d_in[4], out_col, nE, flags, 1, 4);
        mlp_kernel<false><<<mblocksR, 256, 0, stream>>>(
            d_in[0], out_col, d_in[8], d_in[9], d_in[10], d_in[11], d_in[16],
            out_row, NROW, flags, 0, 8, 9, 10, 11, 16);

        hipMemsetAsync(out_col, 0, aggBytes, stream);
        scatter_any<<<sblocks, 256, 0, stream>>>(out_row, src_r2c, dst_r2c,
            d_in[7], out_col, nE, flags, -1, 7);
        residual_add<<<(NROW * DDIM / 4 + 255) / 256, 256, 0, stream>>>(
            out_row, d_in[0], NROW * DDIM / 4, flags, 0);
        mlp_kernel<true><<<mblocksC, 256, 0, stream>>>(
            d_in[1], out_col, d_in[12], d_in[13], d_in[14], d_in[15], d_in[17],
            out_col, NCOL, flags, 1, 12, 13, 14, 15, 17);
    }
}

// Round 13
// 303.384 us; speedup vs baseline: 1.0561x; 1.0094x over previous
//
#include <hip/hip_runtime.h>
#include <hip/hip_bf16.h>

#define NROW 50000
#define NCOL 50000
#define DDIM 128
#define CAP  32   // slots per destination row

typedef __bf16 bf16_t;
typedef __bf16 bf16x2 __attribute__((ext_vector_type(2)));
typedef __bf16 bf16x8 __attribute__((ext_vector_type(8)));
typedef float  f32x4  __attribute__((ext_vector_type(4)));

__device__ __forceinline__ float lrelu(float v) { return v >= 0.f ? v : 0.01f * v; }

__device__ __forceinline__ float ldf(const void* p, size_t i, bool f) {
    return f ? ((const float*)p)[i] : (float)((const bf16_t*)p)[i];
}

// fi: >=0 -> flags[fi]; -1 -> forced f32; -2 -> forced bf16
__device__ __forceinline__ bool dtf(const int* flags, int fi) {
    return (fi == -1) ? true : (fi == -2) ? false : (flags[fi] != 0);
}

// ---------------- D1: dtype detect (18 blocks) + zero counts ---------------
struct TensorTab { const void* p[18]; int n[18]; };

__global__ __launch_bounds__(256) void detect_zero(TensorTab T, int* flags,
                                                   int* z, int zn)
{
    const int tid = threadIdx.x;
    if (blockIdx.x >= 18) {                  // zero countsA|ovCntA|countsB|ovCntB
        int i = (blockIdx.x - 18) * 256 + tid;
        if (i < zn) z[i] = 0;
        return;
    }
    __shared__ int vb, vf;
    const int t = blockIdx.x;
    if (tid == 0) { vb = 0; vf = 0; }
    __syncthreads();
    const int n = T.n[t];
    const bool isFloatArr = (t != 2 && t != 3 && t != 5 && t != 6) && n >= 2;
    if (isFloatArr) {
        int nw = n / 2;
        int wi = (int)(((long long)tid * nw) >> 8);
        unsigned w = ((const unsigned*)T.p[t])[wi];
        unsigned low = w & 0xffffu;
        if (low) {
            int e = (int)((low >> 7) & 0xffu);
            if (e >= 90 && e <= 141) atomicAdd(&vb, 1);
            else                     atomicAdd(&vf, 1);
        }
    }
    __syncthreads();
    if (tid == 0) flags[t] = (isFloatArr && vf > vb) ? 1 : 0; // 1 = f32
}

// ---------------- fill: packed (src,w) int2 slots ---------------------------
__device__ __forceinline__ void fill_edges(
    int e, const int* __restrict__ dst, const int* __restrict__ srcArr,
    const void* __restrict__ wArr, int nE, int* __restrict__ counts,
    int2* __restrict__ slots2, int* __restrict__ ovCnt,
    int* __restrict__ ovList, bool fW)
{
    if (e >= nE) return;
    int d = dst[e];
    int pos = atomicAdd(&counts[d], 1);
    if (pos < CAP) {
        int2 pk;
        pk.x = srcArr[e];
        pk.y = __float_as_int(ldf(wArr, e, fW));
        slots2[(size_t)d * CAP + pos] = pk;
    } else {
        int k = atomicAdd(ovCnt, 1);         // capacity == nE
        ovList[k] = e;
    }
}

struct WPtrs { const void* W[4]; int fi[4]; };

__device__ __forceinline__ void prep_one(WPtrs P, const int* flags,
                                         __bf16* wfp, int slot)
{
    if (slot >= 4 * 2048) return;
    int m = slot >> 11, sIdx = slot & 2047;
    bool f = flags[P.fi[m]] != 0;
    int l = sIdx & 63, combo = sIdx >> 6;
    int ct = combo >> 2, kk = combo & 3;
    int col  = ct * 16 + (l & 15);
    int krow = kk * 32 + (l >> 4) * 8;
    bf16x8 v;
#pragma unroll
    for (int j = 0; j < 8; ++j)
        v[j] = (__bf16)ldf(P.W[m], (size_t)(krow + j) * DDIM + col, f);
    ((bf16x8*)wfp)[slot] = v;
}

__device__ __forceinline__ void convert_one(const void* __restrict__ feat,
                                            __bf16* __restrict__ cbuf,
                                            int i, int n8, bool f)
{
    if (i >= n8) return;
    bf16x8 v;
    if (f) {
        f32x4 a = ((const f32x4*)feat)[i * 2];
        f32x4 c = ((const f32x4*)feat)[i * 2 + 1];
#pragma unroll
        for (int j = 0; j < 4; ++j) { v[j] = (__bf16)a[j]; v[j + 4] = (__bf16)c[j]; }
    } else {
        v = ((const bf16x8*)feat)[i];
    }
    ((bf16x8*)cbuf)[i] = v;
}

// ---------------- D2: convert || fillA interleaved 4:3, prep tail -----------
__global__ __launch_bounds__(1024) void prep_fill_i2(
    WPtrs P, const int* __restrict__ flags, __bf16* __restrict__ wfp,
    const void* __restrict__ feat, __bf16* __restrict__ cbuf, int n8,
    int fiFeat, int cb, int eb, int K7,
    const int* __restrict__ f_dst, const int* __restrict__ f_src,
    const void* __restrict__ f_w, int f_nE, int* __restrict__ f_counts,
    int2* __restrict__ f_slots2, int* __restrict__ f_ovCnt,
    int* __restrict__ f_ovList, int f_fiW)
{
    const int g = blockIdx.x;
    const int tid = threadIdx.x;
    if (g >= K7) {                            // weight B-frag prep
        prep_one(P, flags, wfp, (g - K7) * 1024 + tid);
        return;
    }
    int grp = g / 7, rem = g % 7;
    if (rem < 4) {                            // convert feat table to bf16
        int b = grp * 4 + rem;
        if (b >= cb) return;
        convert_one(feat, cbuf, b * 1024 + tid, n8, dtf(flags, fiFeat));
    } else {                                  // fill stage-1 buckets
        int b = grp * 3 + (rem - 4);
        if (b >= eb) return;
        fill_edges(b * 1024 + tid, f_dst, f_src, f_w, f_nE, f_counts,
                   f_slots2, f_ovCnt, f_ovList, dtf(flags, f_fiW));
    }
}

// ---------------- A7: fused segsum + MLP, 16-wave blocks, 8-deep gather -----
// r10 structure (proven to run) with ONE change: Phase S gather is 8-DEEP
// (4 accumulators, round-2-proven loop shape) -> 8 independent loads in
// flight per wave, 2x r10's MLP. D3 is latency-bound (r10: time invariant
// to bytes), so the extra L2 traffic of deeper pipelining is free.
template <bool RESIDUAL, bool HOUT>
__global__ __launch_bounds__(1024) void mlp_fused2(
    const __bf16* __restrict__ gsrc, const int* __restrict__ counts,
    const int2* __restrict__ slots2, const int* __restrict__ srcArr,
    const int* __restrict__ dstArr, const void* __restrict__ wArr,
    const int* __restrict__ ovList, const int* __restrict__ ovCount, int fiW,
    const void* __restrict__ feat, const void* __restrict__ b1,
    const void* __restrict__ b2, const void* __restrict__ epsp,
    float* __restrict__ out, int N, const int* __restrict__ flags,
    int fiFeat, int fiB1, int fiB2, int fiEps,
    const __bf16* __restrict__ pW1, const __bf16* __restrict__ pW2,
    __bf16* __restrict__ hout,
    int mlpBlocks, int fillBlocks,
    const int* __restrict__ f_dst, const int* __restrict__ f_src,
    const void* __restrict__ f_w, int f_nE, int* __restrict__ f_counts,
    int2* __restrict__ f_slots2, int* __restrict__ f_ovCnt,
    int* __restrict__ f_ovList, int f_fiW)
{
    __shared__ alignas(16) __bf16 At[16 * 136];   // A tile (later: hout stage)
    __shared__ alignas(16) __bf16 H1[16 * 136];   // h1 exchange tile

    const int tid = threadIdx.x;
    int bid;
    if (f_dst) {                              // interleaved roles, 4 mlp : 3 fill
        int grp = (int)blockIdx.x / 7, rem = (int)blockIdx.x % 7;
        if (rem >= 4) {
            int b = grp * 3 + (rem - 4);
            if (b < fillBlocks)
                fill_edges(b * 1024 + tid, f_dst, f_src, f_w, f_nE, f_counts,
                           f_slots2, f_ovCnt, f_ovList, dtf(flags, f_fiW));
            return;
        }
        bid = grp * 4 + rem;
        if (bid >= mlpBlocks) return;
    } else {
        bid = blockIdx.x;
        if (bid >= mlpBlocks) return;
    }

    const bool fF  = flags[fiFeat] != 0;
    const bool fB1 = flags[fiB1] != 0;
    const bool fB2 = flags[fiB2] != 0;
    const bool fE  = flags[fiEps] != 0;

    const int lane = tid & 63;
    const int wave = tid >> 6;                // 0..15
    const int quad = lane >> 4;
    const int r    = lane & 15;
    const int rowBase = bid * 16;
    const float eps1 = 1.f + ldf(epsp, 0, fE);

    // ---- Phase S: gather, ONE row per wave, 8-DEEP pipeline ----
    {
        const bf16x2* fb = (const bf16x2*)gsrc;
        int row = rowBase + wave;
        bf16x2 o;
        if (row < N) {
            int cntRaw = counts[row];
            int cnt = cntRaw > CAP ? CAP : cntRaw;
            int sr = 0; float wv = 0.f;
            if (lane < cnt) {                 // one coalesced 8B lane load
                int2 pk = slots2[(size_t)row * CAP + lane];
                sr = pk.x;
                wv = __int_as_float(pk.y);
            }
            float2 acc0 = {0.f, 0.f}, acc1 = {0.f, 0.f};
            float2 acc2 = {0.f, 0.f}, acc3 = {0.f, 0.f};
            int i = 0;
            for (; i + 8 <= cnt; i += 8) {    // 8 independent loads in flight
                int   a0 = __shfl(sr, i),     a1 = __shfl(sr, i + 1);
                int   a2 = __shfl(sr, i + 2), a3 = __shfl(sr, i + 3);
                int   a4 = __shfl(sr, i + 4), a5 = __shfl(sr, i + 5);
                int   a6 = __shfl(sr, i + 6), a7 = __shfl(sr, i + 7);
                float w0 = __shfl(wv, i),     w1 = __shfl(wv, i + 1);
                float w2 = __shfl(wv, i + 2), w3 = __shfl(wv, i + 3);
                float w4 = __shfl(wv, i + 4), w5 = __shfl(wv, i + 5);
                float w6 = __shfl(wv, i + 6), w7 = __shfl(wv, i + 7);
                bf16x2 v0 = fb[(size_t)a0 * 64 + lane];
                bf16x2 v1 = fb[(size_t)a1 * 64 + lane];
                bf16x2 v2 = fb[(size_t)a2 * 64 + lane];
                bf16x2 v3 = fb[(size_t)a3 * 64 + lane];
                bf16x2 v4 = fb[(size_t)a4 * 64 + lane];
                bf16x2 v5 = fb[(size_t)a5 * 64 + lane];
                bf16x2 v6 = fb[(size_t)a6 * 64 + lane];
                bf16x2 v7 = fb[(size_t)a7 * 64 + lane];
                acc0.x += (float)v0[0] * w0; acc0.y += (float)v0[1] * w0;
                acc1.x += (float)v1[0] * w1; acc1.y += (float)v1[1] * w1;
                acc2.x += (float)v2[0] * w2; acc2.y += (float)v2[1] * w2;
                acc3.x += (float)v3[0] * w3; acc3.y += (float)v3[1] * w3;
                acc0.x += (float)v4[0] * w4; acc0.y += (float)v4[1] * w4;
                acc1.x += (float)v5[0] * w5; acc1.y += (float)v5[1] * w5;
                acc2.x += (float)v6[0] * w6; acc2.y += (float)v6[1] * w6;
                acc3.x += (float)v7[0] * w7; acc3.y += (float)v7[1] * w7;
            }
            if (i + 4 <= cnt) {
                int   a0 = __shfl(sr, i),     a1 = __shfl(sr, i + 1);
                int   a2 = __shfl(sr, i + 2), a3 = __shfl(sr, i + 3);
                float w0 = __shfl(wv, i),     w1 = __shfl(wv, i + 1);
                float w2 = __shfl(wv, i + 2), w3 = __shfl(wv, i + 3);
                bf16x2 v0 = fb[(size_t)a0 * 64 + lane];
                bf16x2 v1 = fb[(size_t)a1 * 64 + lane];
                bf16x2 v2 = fb[(size_t)a2 * 64 + lane];
                bf16x2 v3 = fb[(size_t)a3 * 64 + lane];
                acc0.x += (float)v0[0] * w0; acc0.y += (float)v0[1] * w0;
                acc1.x += (float)v1[0] * w1; acc1.y += (float)v1[1] * w1;
                acc2.x += (float)v2[0] * w2; acc2.y += (float)v2[1] * w2;
                acc3.x += (float)v3[0] * w3; acc3.y += (float)v3[1] * w3;
                i += 4;
            }
            for (; i < cnt; ++i) {
                int   a0 = __shfl(sr, i);
                float w0 = __shfl(wv, i);
                bf16x2 v0 = fb[(size_t)a0 * 64 + lane];
                acc0.x += (float)v0[0] * w0; acc0.y += (float)v0[1] * w0;
            }
            if (cntRaw > CAP) {               // rare: exact overflow scan
                const bool fW = dtf(flags, fiW);
                int nOv = *ovCount;
                for (int k = 0; k < nOv; ++k) {
                    int e = ovList[k];
                    if (dstArr[e] == row) {
                        int s = srcArr[e];
                        float wf = ldf(wArr, e, fW);
                        bf16x2 v = fb[(size_t)s * 64 + lane];
                        acc0.x += (float)v[0] * wf;
                        acc0.y += (float)v[1] * wf;
                    }
                }
            }
            acc0.x += acc1.x; acc0.y += acc1.y;
            acc2.x += acc3.x; acc2.y += acc3.y;
            float ax = acc0.x + acc2.x, ay = acc0.y + acc2.y;
            float f0, f1;
            if (fF) {
                float2 fv = ((const float2*)((const float*)feat +
                             (size_t)row * DDIM))[lane];
                f0 = fv.x; f1 = fv.y;
            } else {
                bf16x2 fv = ((const bf16x2*)((const bf16_t*)feat +
                             (size_t)row * DDIM))[lane];
                f0 = (float)fv[0]; f1 = (float)fv[1];
            }
            o[0] = (__bf16)(f0 * eps1 + ax);
            o[1] = (__bf16)(f1 * eps1 + ay);
        } else {
            o[0] = (__bf16)0.f; o[1] = (__bf16)0.f;
        }
        *(bf16x2*)&At[wave * 136 + lane * 2] = o;
    }
    __syncthreads();

    // ---- layer 1: waves 0-7, one 16-col tile each ----
    const int ct = wave;
    if (wave < 8) {
        bf16x8 a[4];
#pragma unroll
        for (int kk = 0; kk < 4; ++kk)
            a[kk] = *(const bf16x8*)&At[r * 136 + kk * 32 + quad * 8];
        const bf16x8* pw1v = (const bf16x8*)pW1;
        bf16x8 w1f[4];
#pragma unroll
        for (int kk = 0; kk < 4; ++kk)
            w1f[kk] = pw1v[(ct * 4 + kk) * 64 + lane];
        float b1v = ldf(b1, ct * 16 + r, fB1);
        f32x4 acc = {0.f, 0.f, 0.f, 0.f};
#pragma unroll
        for (int kk = 0; kk < 4; ++kk)
            acc = __builtin_amdgcn_mfma_f32_16x16x32_bf16(a[kk], w1f[kk], acc, 0, 0, 0);
#pragma unroll
        for (int gg = 0; gg < 4; ++gg)
            H1[(quad * 4 + gg) * 136 + ct * 16 + r] = (__bf16)lrelu(acc[gg] + b1v);
    }
    __syncthreads();

    // ---- layer 2: waves 0-7 -> out (+residual); HOUT: stage bf16 h in At ---
    if (wave < 8) {
        bf16x8 a2[4];
#pragma unroll
        for (int kk = 0; kk < 4; ++kk)
            a2[kk] = *(const bf16x8*)&H1[r * 136 + kk * 32 + quad * 8];
        const bf16x8* pw2v = (const bf16x8*)pW2;
        bf16x8 w2f[4];
#pragma unroll
        for (int kk = 0; kk < 4; ++kk)
            w2f[kk] = pw2v[(ct * 4 + kk) * 64 + lane];
        float b2v = ldf(b2, ct * 16 + r, fB2);
        f32x4 acc = {0.f, 0.f, 0.f, 0.f};
#pragma unroll
        for (int kk = 0; kk < 4; ++kk)
            acc = __builtin_amdgcn_mfma_f32_16x16x32_bf16(a2[kk], w2f[kk], acc, 0, 0, 0);
#pragma unroll
        for (int gg = 0; gg < 4; ++gg) {
            int row = rowBase + quad * 4 + gg;
            float v = lrelu(acc[gg] + b2v);
            if (HOUT)
                At[(quad * 4 + gg) * 136 + ct * 16 + r] = (__bf16)v;
            if (row < N) {
                int col = ct * 16 + r;
                if (RESIDUAL) v += ldf(feat, (size_t)row * DDIM + col, fF);
                out[(size_t)row * DDIM + col] = v;
            }
        }
    }

    // ---- cooperative coalesced hout store ----
    if (HOUT) {
        __syncthreads();
        if (tid < 256) {                      // 16 rows x 16 chunks of bf16x8
            int row = tid >> 4;
            int k0  = (tid & 15) * 8;
            int g   = rowBase + row;
            if (g < N)
                *(bf16x8*)&hout[(size_t)g * DDIM + k0] =
                    *(const bf16x8*)&At[row * 136 + k0];
        }
    }
}

// =================== round-7 tier-A2 fallback kernels (proven) ==============
__global__ __launch_bounds__(256) void prep_fill(
    WPtrs P, const int* __restrict__ flags, __bf16* __restrict__ wfp,
    const void* __restrict__ feat, __bf16* __restrict__ cbuf, int n8,
    int fiFeat, int cblocks,
    const int* __restrict__ f_dst, const int* __restrict__ f_src,
    const void* __restrict__ f_w, int f_nE, int* __restrict__ f_counts,
    int2* __restrict__ f_slots2, int* __restrict__ f_ovCnt,
    int* __restrict__ f_ovList, int f_fiW)
{
    const int b = blockIdx.x;
    const int tid = threadIdx.x;
    if (b < cblocks) {
        convert_one(feat, cbuf, b * 256 + tid, n8, dtf(flags, fiFeat));
    } else if (b < cblocks + 32) {
        prep_one(P, flags, wfp, (b - cblocks) * 256 + tid);
    } else {
        int e = (b - cblocks - 32) * 256 + tid;
        fill_edges(e, f_dst, f_src, f_w, f_nE, f_counts, f_slots2,
                   f_ovCnt, f_ovList, dtf(flags, f_fiW));
    }
}

__global__ __launch_bounds__(256) void segsum_scan(
    const __bf16* __restrict__ gsrc, const int* __restrict__ counts,
    const int2* __restrict__ slots2, float* __restrict__ agg, int nRows,
    const int* __restrict__ srcArr, const int* __restrict__ dstArr,
    const void* __restrict__ wArr, const int* __restrict__ ovList,
    const int* __restrict__ ovCount, const int* __restrict__ flags, int fiW)
{
    int row = blockIdx.x * 4 + (threadIdx.x >> 6);
    if (row >= nRows) return;
    int lane = threadIdx.x & 63;

    int cntRaw = counts[row];
    int cnt = cntRaw > CAP ? CAP : cntRaw;

    int sr = 0; float wv = 0.f;
    if (lane < cnt) {
        int2 pk = slots2[(size_t)row * CAP + lane];
        sr = pk.x;
        wv = __int_as_float(pk.y);
    }

    float2* ap = (float2*)(agg + (size_t)row * DDIM) + lane;
    float2 acc0 = {0.f, 0.f}, acc1 = {0.f, 0.f};

    const bf16x2* fb = (const bf16x2*)gsrc;
    int i = 0;
    for (; i + 4 <= cnt; i += 4) {
        int   a0 = __shfl(sr, i),     a1 = __shfl(sr, i + 1);
        int   a2 = __shfl(sr, i + 2), a3 = __shfl(sr, i + 3);
        float w0 = __shfl(wv, i),     w1 = __shfl(wv, i + 1);
        float w2 = __shfl(wv, i + 2), w3 = __shfl(wv, i + 3);
        bf16x2 v0 = fb[(size_t)a0 * 64 + lane];
        bf16x2 v1 = fb[(size_t)a1 * 64 + lane];
        bf16x2 v2 = fb[(size_t)a2 * 64 + lane];
        bf16x2 v3 = fb[(size_t)a3 * 64 + lane];
        acc0.x += (float)v0[0] * w0; acc0.y += (float)v0[1] * w0;
        acc1.x += (float)v1[0] * w1; acc1.y += (float)v1[1] * w1;
        acc0.x += (float)v2[0] * w2; acc0.y += (float)v2[1] * w2;
        acc1.x += (float)v3[0] * w3; acc1.y += (float)v3[1] * w3;
    }
    for (; i < cnt; ++i) {
        int   a0 = __shfl(sr, i);
        float w0 = __shfl(wv, i);
        bf16x2 v0 = fb[(size_t)a0 * 64 + lane];
        acc0.x += (float)v0[0] * w0; acc0.y += (float)v0[1] * w0;
    }
    if (cntRaw > CAP) {
        const bool fW = dtf(flags, fiW);
        int nOv = *ovCount;
        for (int k = 0; k < nOv; ++k) {
            int e = ovList[k];
            if (dstArr[e] == row) {
                int s = srcArr[e];
                float wf = ldf(wArr, e, fW);
                bf16x2 v = fb[(size_t)s * 64 + lane];
                acc0.x += (float)v[0] * wf; acc0.y += (float)v[1] * wf;
            }
        }
    }
    acc0.x += acc1.x; acc0.y += acc1.y;
    *ap = acc0;
}

template <bool RESIDUAL, bool HOUT>
__global__ __launch_bounds__(256) void mlp_cs(
    const void* __restrict__ feat, const float* __restrict__ agg,
    const void* __restrict__ b1, const void* __restrict__ b2,
    const void* __restrict__ epsp, float* __restrict__ out, int N,
    const int* __restrict__ flags, int fiFeat, int fiB1, int fiB2, int fiEps,
    const __bf16* __restrict__ pW1, const __bf16* __restrict__ pW2,
    __bf16* __restrict__ hout,
    int mblocks,
    const int* __restrict__ f_dst, const int* __restrict__ f_src,
    const void* __restrict__ f_w, int f_nE, int* __restrict__ f_counts,
    int2* __restrict__ f_slots2, int* __restrict__ f_ovCnt,
    int* __restrict__ f_ovList, int f_fiW)
{
    __shared__ alignas(16) __bf16 At[16 * 136];
    __shared__ alignas(16) __bf16 H1[16 * 136];

    const int tid = threadIdx.x;
    if (f_dst && (int)blockIdx.x >= mblocks) {
        int e = ((int)blockIdx.x - mblocks) * 256 + tid;
        fill_edges(e, f_dst, f_src, f_w, f_nE, f_counts, f_slots2,
                   f_ovCnt, f_ovList, dtf(flags, f_fiW));
        return;
    }

    const bool fF  = flags[fiFeat] != 0;
    const bool fB1 = flags[fiB1] != 0;
    const bool fB2 = flags[fiB2] != 0;
    const bool fE  = flags[fiEps] != 0;

    const int lane = tid & 63;
    const int wave = tid >> 6;
    const int quad = lane >> 4;
    const int r    = lane & 15;
    const int rowBase = blockIdx.x * 16;
    const float eps1 = 1.f + ldf(epsp, 0, fE);

    {
        int row = tid >> 4;
        int k0  = (tid & 15) * 8;
        int g   = rowBase + row;
        bf16x8 av;
        if (g < N) {
            size_t base = (size_t)g * DDIM + k0;
            const f32x4* gp = (const f32x4*)(agg + base);
            f32x4 g0 = gp[0], g1 = gp[1];
            if (fF) {
                const f32x4* fp = (const f32x4*)((const float*)feat + base);
                f32x4 f0 = fp[0], f1 = fp[1];
#pragma unroll
                for (int j = 0; j < 4; ++j) {
                    av[j]     = (__bf16)(f0[j] * eps1 + g0[j]);
                    av[j + 4] = (__bf16)(f1[j] * eps1 + g1[j]);
                }
            } else {
                bf16x8 fv = *(const bf16x8*)((const bf16_t*)feat + base);
#pragma unroll
                for (int j = 0; j < 4; ++j) {
                    av[j]     = (__bf16)((float)fv[j]     * eps1 + g0[j]);
                    av[j + 4] = (__bf16)((float)fv[j + 4] * eps1 + g1[j]);
                }
            }
        } else {
#pragma unroll
            for (int j = 0; j < 8; ++j) av[j] = (__bf16)0.f;
        }
        *(bf16x8*)&At[row * 136 + k0] = av;
    }
    __syncthreads();

    bf16x8 a[4];
#pragma unroll
    for (int kk = 0; kk < 4; ++kk)
        a[kk] = *(const bf16x8*)&At[r * 136 + kk * 32 + quad * 8];

    const int ct0 = wave * 2, ct1 = ct0 + 1;

    const bf16x8* pw1v = (const bf16x8*)pW1;
    bf16x8 wfa[4], wfb[4];
#pragma unroll
    for (int kk = 0; kk < 4; ++kk) {
        wfa[kk] = pw1v[(ct0 * 4 + kk) * 64 + lane];
        wfb[kk] = pw1v[(ct1 * 4 + kk) * 64 + lane];
    }
    float b1a = ldf(b1, ct0 * 16 + r, fB1);
    float b1b = ldf(b1, ct1 * 16 + r, fB1);

    {
        f32x4 acc = {0.f, 0.f, 0.f, 0.f};
#pragma unroll
        for (int kk = 0; kk < 4; ++kk)
            acc = __builtin_amdgcn_mfma_f32_16x16x32_bf16(a[kk], wfa[kk], acc, 0, 0, 0);
#pragma unroll
        for (int gg = 0; gg < 4; ++gg)
            H1[(quad * 4 + gg) * 136 + ct0 * 16 + r] = (__bf16)lrelu(acc[gg] + b1a);
    }
    {
        f32x4 acc = {0.f, 0.f, 0.f, 0.f};
#pragma unroll
        for (int kk = 0; kk < 4; ++kk)
            acc = __builtin_amdgcn_mfma_f32_16x16x32_bf16(a[kk], wfb[kk], acc, 0, 0, 0);
#pragma unroll
        for (int gg = 0; gg < 4; ++gg)
            H1[(quad * 4 + gg) * 136 + ct1 * 16 + r] = (__bf16)lrelu(acc[gg] + b1b);
    }
    __syncthreads();

    bf16x8 a2[4];
#pragma unroll
    for (int kk = 0; kk < 4; ++kk)
        a2[kk] = *(const bf16x8*)&H1[r * 136 + kk * 32 + quad * 8];

    const bf16x8* pw2v = (const bf16x8*)pW2;
#pragma unroll
    for (int kk = 0; kk < 4; ++kk) {
        wfa[kk] = pw2v[(ct0 * 4 + kk) * 64 + lane];
        wfb[kk] = pw2v[(ct1 * 4 + kk) * 64 + lane];
    }
    float b2a = ldf(b2, ct0 * 16 + r, fB2);
    float b2b = ldf(b2, ct1 * 16 + r, fB2);

#pragma unroll
    for (int cp = 0; cp < 2; ++cp) {
        const int ct = cp ? ct1 : ct0;
        f32x4 acc = {0.f, 0.f, 0.f, 0.f};
#pragma unroll
        for (int kk = 0; kk < 4; ++kk)
            acc = __builtin_amdgcn_mfma_f32_16x16x32_bf16(
                a2[kk], cp ? wfb[kk] : wfa[kk], acc, 0, 0, 0);
        float bias = cp ? b2b : b2a;
#pragma unroll
        for (int gg = 0; gg < 4; ++gg) {
            int row = rowBase + quad * 4 + gg;
            float v = lrelu(acc[gg] + bias);
            if (HOUT)
                At[(quad * 4 + gg) * 136 + ct * 16 + r] = (__bf16)v;
            if (row < N) {
                int col = ct * 16 + r;
                if (RESIDUAL) v += ldf(feat, (size_t)row * DDIM + col, fF);
                out[(size_t)row * DDIM + col] = v;
            }
        }
    }

    if (HOUT) {
        __syncthreads();
        int row = tid >> 4;
        int k0  = (tid & 15) * 8;
        int g   = rowBase + row;
        if (g < N)
            *(bf16x8*)&hout[(size_t)g * DDIM + k0] =
                *(const bf16x8*)&At[row * 136 + k0];
    }
}

// ======================= legacy kernels (ws-too-small) ======================
__global__ __launch_bounds__(256) void scatter_any(
    const void* __restrict__ feat, const int* __restrict__ src,
    const int* __restrict__ dst, const void* __restrict__ w,
    float* __restrict__ agg, int nE,
    const int* __restrict__ flags, int fiFeat, int fiW)
{
    const bool fF = dtf(flags, fiFeat);
    const bool fW = dtf(flags, fiW);
    int g = blockIdx.x * 256 + threadIdx.x;
    int e = g >> 5;
    if (e >= nE) return;
    int c = (g & 31) << 2;
    int s = src[e], d = dst[e];
    float wf = ldf(w, e, fW);
    size_t base = (size_t)s * DDIM + c;
    float* ap = agg + (size_t)d * DDIM + c;
    unsafeAtomicAdd(ap + 0, ldf(feat, base + 0, fF) * wf);
    unsafeAtomicAdd(ap + 1, ldf(feat, base + 1, fF) * wf);
    unsafeAtomicAdd(ap + 2, ldf(feat, base + 2, fF) * wf);
    unsafeAtomicAdd(ap + 3, ldf(feat, base + 3, fF) * wf);
}

__global__ __launch_bounds__(256) void residual_add(
    float* __restrict__ out, const void* __restrict__ feat, int n4,
    const int* __restrict__ flags, int fiFeat)
{
    const bool fF = flags[fiFeat] != 0;
    int i = blockIdx.x * 256 + threadIdx.x;
    if (i >= n4) return;
    f32x4 o = ((const f32x4*)out)[i];
    f32x4 r;
#pragma unroll
    for (int j = 0; j < 4; ++j) r[j] = o[j] + ldf(feat, (size_t)i * 4 + j, fF);
    ((f32x4*)out)[i] = r;
}

__device__ __forceinline__ void fill_wfrag(const void* __restrict__ W, bool f,
                                           __bf16* wf, int tid)
{
#pragma unroll
    for (int i = 0; i < 8; ++i) {
        int sIdx  = tid + i * 256;
        int l     = sIdx & 63;
        int combo = sIdx >> 6;
        int ct = combo >> 2, kk = combo & 3;
        int col  = ct * 16 + (l & 15);
        int krow = kk * 32 + (l >> 4) * 8;
        __bf16* dp = wf + (size_t)sIdx * 8;
#pragma unroll
        for (int j = 0; j < 8; ++j)
            dp[j] = (__bf16)ldf(W, (size_t)(krow + j) * DDIM + col, f);
    }
}

template <bool RESIDUAL>
__global__ __launch_bounds__(256) void mlp_kernel(
    const void* __restrict__ feat, const float* __restrict__ agg,
    const void* __restrict__ W1, const void* __restrict__ b1,
    const void* __restrict__ W2, const void* __restrict__ b2,
    const void* __restrict__ epsp, float* __restrict__ out, int N,
    const int* __restrict__ flags,
    int fiFeat, int fiW1, int fiB1, int fiW2, int fiB2, int fiEps)
{
    __shared__ alignas(16) __bf16 wf[32 * 64 * 8];
    __shared__ alignas(16) __bf16 h1t[64 * 136];

    const bool fF  = flags[fiFeat] != 0;
    const bool fB1 = flags[fiB1] != 0;
    const bool fB2 = flags[fiB2] != 0;
    const bool fE  = flags[fiEps] != 0;

    const int tid  = threadIdx.x;
    const int lane = tid & 63;
    const int wave = tid >> 6;
    const int quad = lane >> 4;
    const int r    = lane & 15;

    fill_wfrag(W1, flags[fiW1] != 0, wf, tid);

    const float eps1 = 1.f + ldf(epsp, 0, fE);
    const int rowBase = blockIdx.x * 64 + wave * 16;

    bf16x8 a[4];
    {
        int rowA = rowBase + r;
        if (rowA < N) {
            size_t fb = (size_t)rowA * DDIM + quad * 8;
            const f32x4* gp = (const f32x4*)(agg + fb);
            if (fF) {
                const f32x4* fp = (const f32x4*)((const float*)feat + fb);
#pragma unroll
                for (int kk = 0; kk < 4; ++kk) {
                    f32x4 f0 = fp[kk * 8], f1 = fp[kk * 8 + 1];
                    f32x4 g0 = gp[kk * 8], g1 = gp[kk * 8 + 1];
                    bf16x8 av;
#pragma unroll
                    for (int j = 0; j < 4; ++j) {
                        av[j]     = (__bf16)(f0[j] * eps1 + g0[j]);
                        av[j + 4] = (__bf16)(f1[j] * eps1 + g1[j]);
                    }
                    a[kk] = av;
                }
            } else {
                const bf16x8* fp = (const bf16x8*)((const bf16_t*)feat + fb);
#pragma unroll
                for (int kk = 0; kk < 4; ++kk) {
                    bf16x8 fv = fp[kk * 4];
                    f32x4 g0 = gp[kk * 8], g1 = gp[kk * 8 + 1];
                    bf16x8 av;
#pragma unroll
                    for (int j = 0; j < 4; ++j) {
                        av[j]     = (__bf16)((float)fv[j]     * eps1 + g0[j]);
                        av[j + 4] = (__bf16)((float)fv[j + 4] * eps1 + g1[j]);
                    }
                    a[kk] = av;
                }
            }
        } else {
#pragma unroll
            for (int kk = 0; kk < 4; ++kk)
#pragma unroll
                for (int j = 0; j < 8; ++j) a[kk][j] = (__bf16)0.f;
        }
    }

    __syncthreads();

    const bf16x8* wv = (const bf16x8*)wf;
#pragma unroll
    for (int ct = 0; ct < 8; ++ct) {
        f32x4 acc = {0.f, 0.f, 0.f, 0.f};
#pragma unroll
        for (int kk = 0; kk < 4; ++kk)
            acc = __builtin_amdgcn_mfma_f32_16x16x32_bf16(
                a[kk], wv[(ct * 4 + kk) * 64 + lane], acc, 0, 0, 0);
        float bias = ldf(b1, ct * 16 + r, fB1);
#pragma unroll
        for (int gg = 0; gg < 4; ++gg)
            h1t[(wave * 16 + quad * 4 + gg) * 136 + ct * 16 + r] =
                (__bf16)lrelu(acc[gg] + bias);
    }
    __syncthreads();

    bf16x8 a2[4];
#pragma unroll
    for (int kk = 0; kk < 4; ++kk)
        a2[kk] = *(const bf16x8*)&h1t[(wave * 16 + r) * 136 + kk * 32 + quad * 8];

    fill_wfrag(W2, flags[fiW2] != 0, wf, tid);
    __syncthreads();

#pragma unroll
    for (int ct = 0; ct < 8; ++ct) {
        f32x4 acc = {0.f, 0.f, 0.f, 0.f};
#pragma unroll
        for (int kk = 0; kk < 4; ++kk)
            acc = __builtin_amdgcn_mfma_f32_16x16x32_bf16(
                a2[kk], wv[(ct * 4 + kk) * 64 + lane], acc, 0, 0, 0);
        float bias = ldf(b2, ct * 16 + r, fB2);
#pragma unroll
        for (int gg = 0; gg < 4; ++gg) {
            int row = rowBase + quad * 4 + gg;
            if (row < N) {
                int col = ct * 16 + r;
                float v = lrelu(acc[gg] + bias);
                if (RESIDUAL) v += ldf(feat, (size_t)row * DDIM + col, fF);
                out[(size_t)row * DDIM + col] = v;
            }
        }
    }
}

extern "C" void kernel_launch(void* const* d_in, const int* in_sizes, int n_in,
                              void* d_out, int out_size, void* d_ws, size_t ws_size,
                              hipStream_t stream)
{
    const int* src_c2r = (const int*)d_in[2];
    const int* dst_c2r = (const int*)d_in[3];
    const int* src_r2c = (const int*)d_in[5];
    const int* dst_r2c = (const int*)d_in[6];
    const int nE = in_sizes[2];

    char* wsb = (char*)d_ws;
    int*    flags  = (int*)wsb;
    __bf16* wfprep = (__bf16*)(wsb + 128);

    // ---- A7 layout: cntA|ovCntA|cntB|ovCntB|slots2A|slots2B|ovLA|ovLB|cbufX|cbufH
    int*    cntA   = (int*)(wsb + 128 + 131072);
    int*    ovCntA = cntA + NROW;
    int*    cntB   = cntA + NROW + 8;
    int*    ovCntB = cntA + 2 * NROW + 8;
    size_t  o5 = 128 + 131072 + ((size_t)2 * NROW + 16) * 4;
    o5 = (o5 + 15) & ~(size_t)15;
    int2*   sl2A = (int2*)(wsb + o5);  o5 += (size_t)NROW * CAP * 8;
    int2*   sl2B = (int2*)(wsb + o5);  o5 += (size_t)NROW * CAP * 8;
    int*    ovLA = (int*)(wsb + o5);   o5 += (size_t)nE * 4;
    int*    ovLB = (int*)(wsb + o5);   o5 += (size_t)nE * 4;
    o5 = (o5 + 15) & ~(size_t)15;
    __bf16* cbX  = (__bf16*)(wsb + o5); o5 += (size_t)NCOL * DDIM * 2;
    __bf16* cbH  = (__bf16*)(wsb + o5); o5 += (size_t)NROW * DDIM * 2;
    const size_t NEED_A7 = o5;

    // ---- A2 (round-7) layout: cntA|ovCntA|cntB|ovCntB|slots2|ovLA|ovLB|cbuf
    size_t  ofsA2   = 128 + 131072 + ((size_t)2 * NROW + 16) * 4;
    ofsA2 = (ofsA2 + 15) & ~(size_t)15;
    int2*   slots2A2  = (int2*)(wsb + ofsA2);
    size_t  ofsOvA2   = ofsA2 + (size_t)NROW * CAP * 8;
    int*    ovListA2  = (int*)(wsb + ofsOvA2);
    int*    ovListB2  = ovListA2 + nE;
    size_t  ofsCbA2   = (ofsOvA2 + (size_t)nE * 8 + 15) & ~(size_t)15;
    __bf16* cbufA2    = (__bf16*)(wsb + ofsCbA2);
    const size_t NEED_A2 = ofsCbA2 + (size_t)NROW * DDIM * 2;

    const bool tierA7 = ws_size >= NEED_A7;
    const bool tierA2 = ws_size >= NEED_A2;

    TensorTab T;
    for (int i = 0; i < 18; ++i) { T.p[i] = d_in[i]; T.n[i] = in_sizes[i]; }

    float* out_row = (float*)d_out;
    float* out_col = out_row + (size_t)NROW * DDIM;
    const size_t aggBytes = (size_t)NROW * DDIM * sizeof(float);

    const int eblocks  = (nE + 255) / 256;
    const int sblocks  = (nE * 32 + 255) / 256;
    const int mblocksR = (NROW + 63) / 64;
    const int mblocksC = (NCOL + 63) / 64;
    const int csR      = (NROW + 15) / 16;
    const int csC      = (NCOL + 15) / 16;
    const int gblocksR = (NROW + 3) / 4;
    const int gblocksC = (NCOL + 3) / 4;
    const int cblocks  = (NCOL * DDIM / 8 + 255) / 256;
    const int zn2      = 2 * NROW + 16;
    const int zb2      = (zn2 + 255) / 256;

    WPtrs P;
    P.W[0] = d_in[8];  P.fi[0] = 8;
    P.W[1] = d_in[10]; P.fi[1] = 10;
    P.W[2] = d_in[12]; P.fi[2] = 12;
    P.W[3] = d_in[14]; P.fi[3] = 14;

    if (tierA7) {
        const int n8  = NCOL * DDIM / 8;              // 800000
        const int cb4 = (n8 + 1023) / 1024;           // convert blocks (1024t)
        const int eb4 = (nE + 1023) / 1024;           // fill blocks (1024t)
        // D1: detect dtypes || zero cntA/ovCntA/cntB/ovCntB
        detect_zero<<<18 + zb2, 256, 0, stream>>>(T, flags, cntA, zn2);
        // D2: convert cbufX || fillA (packed), interleaved 4:3; prep at tail
        {
            int ka = (cb4 + 3) / 4, kb = (eb4 + 2) / 3;
            int K = ka > kb ? ka : kb;
            prep_fill_i2<<<7 * K + 8, 1024, 0, stream>>>(
                P, flags, wfprep, d_in[1], cbX, n8, 1, cb4, eb4, 7 * K,
                dst_c2r, src_c2r, d_in[4], nE, cntA, sl2A, ovCntA, ovLA, 4);
        }
        // D3: fused segsumA (8-deep) + mlp1 (out_row = h+feat, cbufH = h bf16)
        //     || fillB (packed), interleaved 4:3
        {
            int ka = (csR + 3) / 4, kb = (eb4 + 2) / 3;
            int K = ka > kb ? ka : kb;
            mlp_fused2<true, true><<<7 * K, 1024, 0, stream>>>(
                cbX, cntA, sl2A, src_c2r, dst_c2r, d_in[4], ovLA, ovCntA, 4,
                d_in[0], d_in[9], d_in[11], d_in[16],
                out_row, NROW, flags, 0, 9, 11, 16,
                wfprep + 0 * 16384, wfprep + 1 * 16384, cbH,
                csR, eb4, dst_r2c, src_r2c, d_in[7], nE, cntB, sl2B,
                ovCntB, ovLB, 7);
        }
        // D4: fused segsumB (8-deep) + mlp2 -> out_col
        mlp_fused2<true, false><<<csC, 1024, 0, stream>>>(
            cbH, cntB, sl2B, src_r2c, dst_r2c, d_in[7], ovLB, ovCntB, 7,
            d_in[1], d_in[13], d_in[15], d_in[17],
            out_col, NCOL, flags, 1, 13, 15, 17,
            wfprep + 2 * 16384, wfprep + 3 * 16384, nullptr,
            csC, 0, nullptr, nullptr, nullptr, 0, nullptr, nullptr,
            nullptr, nullptr, 0);
    } else if (tierA2) {
        // round-7 proven path
        detect_zero<<<18 + zb2, 256, 0, stream>>>(T, flags, cntA, zn2);
        prep_fill<<<cblocks + 32 + eblocks, 256, 0, stream>>>(
            P, flags, wfprep, d_in[1], cbufA2, NCOL * DDIM / 8, 1, cblocks,
            dst_c2r, src_c2r, d_in[4], nE, cntA, slots2A2, ovCntA,
            ovListA2, 4);
        segsum_scan<<<gblocksR, 256, 0, stream>>>(cbufA2, cntA, slots2A2,
            out_col, NROW, src_c2r, dst_c2r, d_in[4], ovListA2, ovCntA,
            flags, 4);
        mlp_cs<true, true><<<csR + eblocks, 256, 0, stream>>>(
            d_in[0], out_col, d_in[9], d_in[11], d_in[16],
            out_row, NROW, flags, 0, 9, 11, 16,
            wfprep + 0 * 16384, wfprep + 1 * 16384, cbufA2,
            csR, dst_r2c, src_r2c, d_in[7], nE, cntB, slots2A2,
            ovCntB, ovListB2, 7);
        segsum_scan<<<gblocksC, 256, 0, stream>>>(cbufA2, cntB, slots2A2,
            out_col, NCOL, src_r2c, dst_r2c, d_in[7], ovListB2, ovCntB,
            flags, 7);
        mlp_cs<true, false><<<csC, 256, 0, stream>>>(
            d_in[1], out_col, d_in[13], d_in[15], d_in[17],
            out_col, NCOL, flags, 1, 13, 15, 17,
            wfprep + 2 * 16384, wfprep + 3 * 16384, nullptr,
            csC, nullptr, nullptr, nullptr, 0, nullptr, nullptr,
            nullptr, nullptr, 0);
    } else {
        // legacy path
        detect_zero<<<18, 256, 0, stream>>>(T, flags, nullptr, 0);
        hipMemsetAsync(out_col, 0, aggBytes, stream);
        scatter_any<<<sblocks, 256, 0, stream>>>(d_in[1], src_c2r, dst_c2r,
            d_in[4], out_col, nE, flags, 1, 4);
        mlp_kernel<false><<<mblocksR, 256, 0, stream>>>(
            d_in[0], out_col, d_in[8], d_in[9], d_in[10], d_in[11], d_in[16],
            out_row, NROW, flags, 0, 8, 9, 10, 11, 16);

        hipMemsetAsync(out_col, 0, aggBytes, stream);
        scatter_any<<<sblocks, 256, 0, stream>>>(out_row, src_r2c, dst_r2c,
            d_in[7], out_col, nE, flags, -1, 7);
        residual_add<<<(NROW * DDIM / 4 + 255) / 256, 256, 0, stream>>>(
            out_row, d_in[0], NROW * DDIM / 4, flags, 0);
        mlp_kernel<true><<<mblocksC, 256, 0, stream>>>(
            d_in[1], out_col, d_in[12], d_in[13], d_in[14], d_in[15], d_in[17],
            out_col, NCOL, flags, 1, 12, 13, 14, 15, 17);
    }
}

// Round 14
// 299.867 us; speedup vs baseline: 1.0685x; 1.0117x over previous
//
#include <hip/hip_runtime.h>
#include <hip/hip_bf16.h>

#define NROW 50000
#define NCOL 50000
#define DDIM 128
#define CAP  32   // slots per destination row

typedef __bf16 bf16_t;
typedef __bf16 bf16x2 __attribute__((ext_vector_type(2)));
typedef __bf16 bf16x8 __attribute__((ext_vector_type(8)));
typedef float  f32x4  __attribute__((ext_vector_type(4)));

__device__ __forceinline__ float lrelu(float v) { return v >= 0.f ? v : 0.01f * v; }

__device__ __forceinline__ float ldf(const void* p, size_t i, bool f) {
    return f ? ((const float*)p)[i] : (float)((const bf16_t*)p)[i];
}

// fi: >=0 -> flags[fi]; -1 -> forced f32; -2 -> forced bf16
__device__ __forceinline__ bool dtf(const int* flags, int fi) {
    return (fi == -1) ? true : (fi == -2) ? false : (flags[fi] != 0);
}

// ---------------- D1: dtype detect (18 blocks) + zero counts ---------------
struct TensorTab { const void* p[18]; int n[18]; };

__global__ __launch_bounds__(256) void detect_zero(TensorTab T, int* flags,
                                                   int* z, int zn)
{
    const int tid = threadIdx.x;
    if (blockIdx.x >= 18) {                  // zero countsA|ovCntA|countsB|ovCntB
        int i = (blockIdx.x - 18) * 256 + tid;
        if (i < zn) z[i] = 0;
        return;
    }
    __shared__ int vb, vf;
    const int t = blockIdx.x;
    if (tid == 0) { vb = 0; vf = 0; }
    __syncthreads();
    const int n = T.n[t];
    const bool isFloatArr = (t != 2 && t != 3 && t != 5 && t != 6) && n >= 2;
    if (isFloatArr) {
        int nw = n / 2;
        int wi = (int)(((long long)tid * nw) >> 8);
        unsigned w = ((const unsigned*)T.p[t])[wi];
        unsigned low = w & 0xffffu;
        if (low) {
            int e = (int)((low >> 7) & 0xffu);
            if (e >= 90 && e <= 141) atomicAdd(&vb, 1);
            else                     atomicAdd(&vf, 1);
        }
    }
    __syncthreads();
    if (tid == 0) flags[t] = (isFloatArr && vf > vb) ? 1 : 0; // 1 = f32
}

// ---------------- fill: packed (src,w) int2 slots ---------------------------
__device__ __forceinline__ void fill_edges(
    int e, const int* __restrict__ dst, const int* __restrict__ srcArr,
    const void* __restrict__ wArr, int nE, int* __restrict__ counts,
    int2* __restrict__ slots2, int* __restrict__ ovCnt,
    int* __restrict__ ovList, bool fW)
{
    if (e >= nE) return;
    int d = dst[e];
    int pos = atomicAdd(&counts[d], 1);
    if (pos < CAP) {
        int2 pk;
        pk.x = srcArr[e];
        pk.y = __float_as_int(ldf(wArr, e, fW));
        slots2[(size_t)d * CAP + pos] = pk;
    } else {
        int k = atomicAdd(ovCnt, 1);         // capacity == nE
        ovList[k] = e;
    }
}

struct WPtrs { const void* W[4]; int fi[4]; };

__device__ __forceinline__ void prep_one(WPtrs P, const int* flags,
                                         __bf16* wfp, int slot)
{
    if (slot >= 4 * 2048) return;
    int m = slot >> 11, sIdx = slot & 2047;
    bool f = flags[P.fi[m]] != 0;
    int l = sIdx & 63, combo = sIdx >> 6;
    int ct = combo >> 2, kk = combo & 3;
    int col  = ct * 16 + (l & 15);
    int krow = kk * 32 + (l >> 4) * 8;
    bf16x8 v;
#pragma unroll
    for (int j = 0; j < 8; ++j)
        v[j] = (__bf16)ldf(P.W[m], (size_t)(krow + j) * DDIM + col, f);
    ((bf16x8*)wfp)[slot] = v;
}

__device__ __forceinline__ void convert_one(const void* __restrict__ feat,
                                            __bf16* __restrict__ cbuf,
                                            int i, int n8, bool f)
{
    if (i >= n8) return;
    bf16x8 v;
    if (f) {
        f32x4 a = ((const f32x4*)feat)[i * 2];
        f32x4 c = ((const f32x4*)feat)[i * 2 + 1];
#pragma unroll
        for (int j = 0; j < 4; ++j) { v[j] = (__bf16)a[j]; v[j + 4] = (__bf16)c[j]; }
    } else {
        v = ((const bf16x8*)feat)[i];
    }
    ((bf16x8*)cbuf)[i] = v;
}

// ---------------- D2: convert || fillA interleaved 4:3, prep tail -----------
__global__ __launch_bounds__(1024) void prep_fill_i2(
    WPtrs P, const int* __restrict__ flags, __bf16* __restrict__ wfp,
    const void* __restrict__ feat, __bf16* __restrict__ cbuf, int n8,
    int fiFeat, int cb, int eb, int K7,
    const int* __restrict__ f_dst, const int* __restrict__ f_src,
    const void* __restrict__ f_w, int f_nE, int* __restrict__ f_counts,
    int2* __restrict__ f_slots2, int* __restrict__ f_ovCnt,
    int* __restrict__ f_ovList, int f_fiW)
{
    const int g = blockIdx.x;
    const int tid = threadIdx.x;
    if (g >= K7) {                            // weight B-frag prep
        prep_one(P, flags, wfp, (g - K7) * 1024 + tid);
        return;
    }
    int grp = g / 7, rem = g % 7;
    if (rem < 4) {                            // convert feat table to bf16
        int b = grp * 4 + rem;
        if (b >= cb) return;
        convert_one(feat, cbuf, b * 1024 + tid, n8, dtf(flags, fiFeat));
    } else {                                  // fill stage-1 buckets
        int b = grp * 3 + (rem - 4);
        if (b >= eb) return;
        fill_edges(b * 1024 + tid, f_dst, f_src, f_w, f_nE, f_counts,
                   f_slots2, f_ovCnt, f_ovList, dtf(flags, f_fiW));
    }
}

// ---------------- D3/D5: segsum (256t, 4 rows/block) || optional fill -------
// De-fused gather back in its proven fast regime (12.5K blocks, 50K gather
// waves, 8 blocks/CU). fill role (for the NEXT stage) interleaved 4:3 —
// both latency-bound, no data conflict (separate slot buffers).
__global__ __launch_bounds__(256) void segsum_fill_i(
    const __bf16* __restrict__ gsrc, const int* __restrict__ counts,
    const int2* __restrict__ slots2, float* __restrict__ agg, int nRows,
    const int* __restrict__ srcArr, const int* __restrict__ dstArr,
    const void* __restrict__ wArr, const int* __restrict__ ovList,
    const int* __restrict__ ovCount, const int* __restrict__ flags, int fiW,
    int segBlocks, int fillBlocks,
    const int* __restrict__ f_dst, const int* __restrict__ f_src,
    const void* __restrict__ f_w, int f_nE, int* __restrict__ f_counts,
    int2* __restrict__ f_slots2, int* __restrict__ f_ovCnt,
    int* __restrict__ f_ovList, int f_fiW)
{
    const int tid = threadIdx.x;
    int bid;
    if (f_dst) {                              // interleaved roles, 4 seg : 3 fill
        int grp = (int)blockIdx.x / 7, rem = (int)blockIdx.x % 7;
        if (rem >= 4) {
            int b = grp * 3 + (rem - 4);
            if (b < fillBlocks)
                fill_edges(b * 256 + tid, f_dst, f_src, f_w, f_nE, f_counts,
                           f_slots2, f_ovCnt, f_ovList, dtf(flags, f_fiW));
            return;
        }
        bid = grp * 4 + rem;
        if (bid >= segBlocks) return;
    } else {
        bid = blockIdx.x;
        if (bid >= segBlocks) return;
    }

    int row = bid * 4 + (tid >> 6);
    if (row >= nRows) return;
    int lane = tid & 63;

    int cntRaw = counts[row];
    int cnt = cntRaw > CAP ? CAP : cntRaw;

    int sr = 0; float wv = 0.f;
    if (lane < cnt) {
        int2 pk = slots2[(size_t)row * CAP + lane];
        sr = pk.x;
        wv = __int_as_float(pk.y);
    }

    float2* ap = (float2*)(agg + (size_t)row * DDIM) + lane;
    float2 acc0 = {0.f, 0.f}, acc1 = {0.f, 0.f};

    const bf16x2* fb = (const bf16x2*)gsrc;
    int i = 0;
    for (; i + 4 <= cnt; i += 4) {
        int   a0 = __shfl(sr, i),     a1 = __shfl(sr, i + 1);
        int   a2 = __shfl(sr, i + 2), a3 = __shfl(sr, i + 3);
        float w0 = __shfl(wv, i),     w1 = __shfl(wv, i + 1);
        float w2 = __shfl(wv, i + 2), w3 = __shfl(wv, i + 3);
        bf16x2 v0 = fb[(size_t)a0 * 64 + lane];
        bf16x2 v1 = fb[(size_t)a1 * 64 + lane];
        bf16x2 v2 = fb[(size_t)a2 * 64 + lane];
        bf16x2 v3 = fb[(size_t)a3 * 64 + lane];
        acc0.x += (float)v0[0] * w0; acc0.y += (float)v0[1] * w0;
        acc1.x += (float)v1[0] * w1; acc1.y += (float)v1[1] * w1;
        acc0.x += (float)v2[0] * w2; acc0.y += (float)v2[1] * w2;
        acc1.x += (float)v3[0] * w3; acc1.y += (float)v3[1] * w3;
    }
    for (; i < cnt; ++i) {
        int   a0 = __shfl(sr, i);
        float w0 = __shfl(wv, i);
        bf16x2 v0 = fb[(size_t)a0 * 64 + lane];
        acc0.x += (float)v0[0] * w0; acc0.y += (float)v0[1] * w0;
    }
    if (cntRaw > CAP) {                      // rare: exact overflow scan
        const bool fW = dtf(flags, fiW);
        int nOv = *ovCount;
        for (int k = 0; k < nOv; ++k) {
            int e = ovList[k];
            if (dstArr[e] == row) {
                int s = srcArr[e];
                float wf = ldf(wArr, e, fW);
                bf16x2 v = fb[(size_t)s * 64 + lane];
                acc0.x += (float)v[0] * wf; acc0.y += (float)v[1] * wf;
            }
        }
    }
    acc0.x += acc1.x; acc0.y += acc1.y;
    *ap = acc0;
}

// ---------------- D4/D6: column-split MLP (r7-proven) ----------------------
template <bool RESIDUAL, bool HOUT>
__global__ __launch_bounds__(256) void mlp_cs(
    const void* __restrict__ feat, const float* __restrict__ agg,
    const void* __restrict__ b1, const void* __restrict__ b2,
    const void* __restrict__ epsp, float* __restrict__ out, int N,
    const int* __restrict__ flags, int fiFeat, int fiB1, int fiB2, int fiEps,
    const __bf16* __restrict__ pW1, const __bf16* __restrict__ pW2,
    __bf16* __restrict__ hout,
    int mblocks,
    const int* __restrict__ f_dst, const int* __restrict__ f_src,
    const void* __restrict__ f_w, int f_nE, int* __restrict__ f_counts,
    int2* __restrict__ f_slots2, int* __restrict__ f_ovCnt,
    int* __restrict__ f_ovList, int f_fiW)
{
    __shared__ alignas(16) __bf16 At[16 * 136];
    __shared__ alignas(16) __bf16 H1[16 * 136];

    const int tid = threadIdx.x;
    if (f_dst && (int)blockIdx.x >= mblocks) {
        int e = ((int)blockIdx.x - mblocks) * 256 + tid;
        fill_edges(e, f_dst, f_src, f_w, f_nE, f_counts, f_slots2,
                   f_ovCnt, f_ovList, dtf(flags, f_fiW));
        return;
    }

    const bool fF  = flags[fiFeat] != 0;
    const bool fB1 = flags[fiB1] != 0;
    const bool fB2 = flags[fiB2] != 0;
    const bool fE  = flags[fiEps] != 0;

    const int lane = tid & 63;
    const int wave = tid >> 6;
    const int quad = lane >> 4;
    const int r    = lane & 15;
    const int rowBase = blockIdx.x * 16;
    const float eps1 = 1.f + ldf(epsp, 0, fE);

    {
        int row = tid >> 4;
        int k0  = (tid & 15) * 8;
        int g   = rowBase + row;
        bf16x8 av;
        if (g < N) {
            size_t base = (size_t)g * DDIM + k0;
            const f32x4* gp = (const f32x4*)(agg + base);
            f32x4 g0 = gp[0], g1 = gp[1];
            if (fF) {
                const f32x4* fp = (const f32x4*)((const float*)feat + base);
                f32x4 f0 = fp[0], f1 = fp[1];
#pragma unroll
                for (int j = 0; j < 4; ++j) {
                    av[j]     = (__bf16)(f0[j] * eps1 + g0[j]);
                    av[j + 4] = (__bf16)(f1[j] * eps1 + g1[j]);
                }
            } else {
                bf16x8 fv = *(const bf16x8*)((const bf16_t*)feat + base);
#pragma unroll
                for (int j = 0; j < 4; ++j) {
                    av[j]     = (__bf16)((float)fv[j]     * eps1 + g0[j]);
                    av[j + 4] = (__bf16)((float)fv[j + 4] * eps1 + g1[j]);
                }
            }
        } else {
#pragma unroll
            for (int j = 0; j < 8; ++j) av[j] = (__bf16)0.f;
        }
        *(bf16x8*)&At[row * 136 + k0] = av;
    }
    __syncthreads();

    bf16x8 a[4];
#pragma unroll
    for (int kk = 0; kk < 4; ++kk)
        a[kk] = *(const bf16x8*)&At[r * 136 + kk * 32 + quad * 8];

    const int ct0 = wave * 2, ct1 = ct0 + 1;

    const bf16x8* pw1v = (const bf16x8*)pW1;
    bf16x8 wfa[4], wfb[4];
#pragma unroll
    for (int kk = 0; kk < 4; ++kk) {
        wfa[kk] = pw1v[(ct0 * 4 + kk) * 64 + lane];
        wfb[kk] = pw1v[(ct1 * 4 + kk) * 64 + lane];
    }
    float b1a = ldf(b1, ct0 * 16 + r, fB1);
    float b1b = ldf(b1, ct1 * 16 + r, fB1);

    {
        f32x4 acc = {0.f, 0.f, 0.f, 0.f};
#pragma unroll
        for (int kk = 0; kk < 4; ++kk)
            acc = __builtin_amdgcn_mfma_f32_16x16x32_bf16(a[kk], wfa[kk], acc, 0, 0, 0);
#pragma unroll
        for (int gg = 0; gg < 4; ++gg)
            H1[(quad * 4 + gg) * 136 + ct0 * 16 + r] = (__bf16)lrelu(acc[gg] + b1a);
    }
    {
        f32x4 acc = {0.f, 0.f, 0.f, 0.f};
#pragma unroll
        for (int kk = 0; kk < 4; ++kk)
            acc = __builtin_amdgcn_mfma_f32_16x16x32_bf16(a[kk], wfb[kk], acc, 0, 0, 0);
#pragma unroll
        for (int gg = 0; gg < 4; ++gg)
            H1[(quad * 4 + gg) * 136 + ct1 * 16 + r] = (__bf16)lrelu(acc[gg] + b1b);
    }
    __syncthreads();

    bf16x8 a2[4];
#pragma unroll
    for (int kk = 0; kk < 4; ++kk)
        a2[kk] = *(const bf16x8*)&H1[r * 136 + kk * 32 + quad * 8];

    const bf16x8* pw2v = (const bf16x8*)pW2;
#pragma unroll
    for (int kk = 0; kk < 4; ++kk) {
        wfa[kk] = pw2v[(ct0 * 4 + kk) * 64 + lane];
        wfb[kk] = pw2v[(ct1 * 4 + kk) * 64 + lane];
    }
    float b2a = ldf(b2, ct0 * 16 + r, fB2);
    float b2b = ldf(b2, ct1 * 16 + r, fB2);

#pragma unroll
    for (int cp = 0; cp < 2; ++cp) {
        const int ct = cp ? ct1 : ct0;
        f32x4 acc = {0.f, 0.f, 0.f, 0.f};
#pragma unroll
        for (int kk = 0; kk < 4; ++kk)
            acc = __builtin_amdgcn_mfma_f32_16x16x32_bf16(
                a2[kk], cp ? wfb[kk] : wfa[kk], acc, 0, 0, 0);
        float bias = cp ? b2b : b2a;
#pragma unroll
        for (int gg = 0; gg < 4; ++gg) {
            int row = rowBase + quad * 4 + gg;
            float v = lrelu(acc[gg] + bias);
            if (HOUT)
                At[(quad * 4 + gg) * 136 + ct * 16 + r] = (__bf16)v;
            if (row < N) {
                int col = ct * 16 + r;
                if (RESIDUAL) v += ldf(feat, (size_t)row * DDIM + col, fF);
                out[(size_t)row * DDIM + col] = v;
            }
        }
    }

    if (HOUT) {
        __syncthreads();
        int row = tid >> 4;
        int k0  = (tid & 15) * 8;
        int g   = rowBase + row;
        if (g < N)
            *(bf16x8*)&hout[(size_t)g * DDIM + k0] =
                *(const bf16x8*)&At[row * 136 + k0];
    }
}

// =================== round-7 tier-A2 fallback kernels (proven) ==============
__global__ __launch_bounds__(256) void prep_fill(
    WPtrs P, const int* __restrict__ flags, __bf16* __restrict__ wfp,
    const void* __restrict__ feat, __bf16* __restrict__ cbuf, int n8,
    int fiFeat, int cblocks,
    const int* __restrict__ f_dst, const int* __restrict__ f_src,
    const void* __restrict__ f_w, int f_nE, int* __restrict__ f_counts,
    int2* __restrict__ f_slots2, int* __restrict__ f_ovCnt,
    int* __restrict__ f_ovList, int f_fiW)
{
    const int b = blockIdx.x;
    const int tid = threadIdx.x;
    if (b < cblocks) {
        convert_one(feat, cbuf, b * 256 + tid, n8, dtf(flags, fiFeat));
    } else if (b < cblocks + 32) {
        prep_one(P, flags, wfp, (b - cblocks) * 256 + tid);
    } else {
        int e = (b - cblocks - 32) * 256 + tid;
        fill_edges(e, f_dst, f_src, f_w, f_nE, f_counts, f_slots2,
                   f_ovCnt, f_ovList, dtf(flags, f_fiW));
    }
}

// ======================= legacy kernels (ws-too-small) ======================
__global__ __launch_bounds__(256) void scatter_any(
    const void* __restrict__ feat, const int* __restrict__ src,
    const int* __restrict__ dst, const void* __restrict__ w,
    float* __restrict__ agg, int nE,
    const int* __restrict__ flags, int fiFeat, int fiW)
{
    const bool fF = dtf(flags, fiFeat);
    const bool fW = dtf(flags, fiW);
    int g = blockIdx.x * 256 + threadIdx.x;
    int e = g >> 5;
    if (e >= nE) return;
    int c = (g & 31) << 2;
    int s = src[e], d = dst[e];
    float wf = ldf(w, e, fW);
    size_t base = (size_t)s * DDIM + c;
    float* ap = agg + (size_t)d * DDIM + c;
    unsafeAtomicAdd(ap + 0, ldf(feat, base + 0, fF) * wf);
    unsafeAtomicAdd(ap + 1, ldf(feat, base + 1, fF) * wf);
    unsafeAtomicAdd(ap + 2, ldf(feat, base + 2, fF) * wf);
    unsafeAtomicAdd(ap + 3, ldf(feat, base + 3, fF) * wf);
}

__global__ __launch_bounds__(256) void residual_add(
    float* __restrict__ out, const void* __restrict__ feat, int n4,
    const int* __restrict__ flags, int fiFeat)
{
    const bool fF = flags[fiFeat] != 0;
    int i = blockIdx.x * 256 + threadIdx.x;
    if (i >= n4) return;
    f32x4 o = ((const f32x4*)out)[i];
    f32x4 r;
#pragma unroll
    for (int j = 0; j < 4; ++j) r[j] = o[j] + ldf(feat, (size_t)i * 4 + j, fF);
    ((f32x4*)out)[i] = r;
}

__device__ __forceinline__ void fill_wfrag(const void* __restrict__ W, bool f,
                                           __bf16* wf, int tid)
{
#pragma unroll
    for (int i = 0; i < 8; ++i) {
        int sIdx  = tid + i * 256;
        int l     = sIdx & 63;
        int combo = sIdx >> 6;
        int ct = combo >> 2, kk = combo & 3;
        int col  = ct * 16 + (l & 15);
        int krow = kk * 32 + (l >> 4) * 8;
        __bf16* dp = wf + (size_t)sIdx * 8;
#pragma unroll
        for (int j = 0; j < 8; ++j)
            dp[j] = (__bf16)ldf(W, (size_t)(krow + j) * DDIM + col, f);
    }
}

template <bool RESIDUAL>
__global__ __launch_bounds__(256) void mlp_kernel(
    const void* __restrict__ feat, const float* __restrict__ agg,
    const void* __restrict__ W1, const void* __restrict__ b1,
    const void* __restrict__ W2, const void* __restrict__ b2,
    const void* __restrict__ epsp, float* __restrict__ out, int N,
    const int* __restrict__ flags,
    int fiFeat, int fiW1, int fiB1, int fiW2, int fiB2, int fiEps)
{
    __shared__ alignas(16) __bf16 wf[32 * 64 * 8];
    __shared__ alignas(16) __bf16 h1t[64 * 136];

    const bool fF  = flags[fiFeat] != 0;
    const bool fB1 = flags[fiB1] != 0;
    const bool fB2 = flags[fiB2] != 0;
    const bool fE  = flags[fiEps] != 0;

    const int tid  = threadIdx.x;
    const int lane = tid & 63;
    const int wave = tid >> 6;
    const int quad = lane >> 4;
    const int r    = lane & 15;

    fill_wfrag(W1, flags[fiW1] != 0, wf, tid);

    const float eps1 = 1.f + ldf(epsp, 0, fE);
    const int rowBase = blockIdx.x * 64 + wave * 16;

    bf16x8 a[4];
    {
        int rowA = rowBase + r;
        if (rowA < N) {
            size_t fb = (size_t)rowA * DDIM + quad * 8;
            const f32x4* gp = (const f32x4*)(agg + fb);
            if (fF) {
                const f32x4* fp = (const f32x4*)((const float*)feat + fb);
#pragma unroll
                for (int kk = 0; kk < 4; ++kk) {
                    f32x4 f0 = fp[kk * 8], f1 = fp[kk * 8 + 1];
                    f32x4 g0 = gp[kk * 8], g1 = gp[kk * 8 + 1];
                    bf16x8 av;
#pragma unroll
                    for (int j = 0; j < 4; ++j) {
                        av[j]     = (__bf16)(f0[j] * eps1 + g0[j]);
                        av[j + 4] = (__bf16)(f1[j] * eps1 + g1[j]);
                    }
                    a[kk] = av;
                }
            } else {
                const bf16x8* fp = (const bf16x8*)((const bf16_t*)feat + fb);
#pragma unroll
                for (int kk = 0; kk < 4; ++kk) {
                    bf16x8 fv = fp[kk * 4];
                    f32x4 g0 = gp[kk * 8], g1 = gp[kk * 8 + 1];
                    bf16x8 av;
#pragma unroll
                    for (int j = 0; j < 4; ++j) {
                        av[j]     = (__bf16)((float)fv[j]     * eps1 + g0[j]);
                        av[j + 4] = (__bf16)((float)fv[j + 4] * eps1 + g1[j]);
                    }
                    a[kk] = av;
                }
            }
        } else {
#pragma unroll
            for (int kk = 0; kk < 4; ++kk)
#pragma unroll
                for (int j = 0; j < 8; ++j) a[kk][j] = (__bf16)0.f;
        }
    }

    __syncthreads();

    const bf16x8* wv = (const bf16x8*)wf;
#pragma unroll
    for (int ct = 0; ct < 8; ++ct) {
        f32x4 acc = {0.f, 0.f, 0.f, 0.f};
#pragma unroll
        for (int kk = 0; kk < 4; ++kk)
            acc = __builtin_amdgcn_mfma_f32_16x16x32_bf16(
                a[kk], wv[(ct * 4 + kk) * 64 + lane], acc, 0, 0, 0);
        float bias = ldf(b1, ct * 16 + r, fB1);
#pragma unroll
        for (int gg = 0; gg < 4; ++gg)
            h1t[(wave * 16 + quad * 4 + gg) * 136 + ct * 16 + r] =
                (__bf16)lrelu(acc[gg] + bias);
    }
    __syncthreads();

    bf16x8 a2[4];
#pragma unroll
    for (int kk = 0; kk < 4; ++kk)
        a2[kk] = *(const bf16x8*)&h1t[(wave * 16 + r) * 136 + kk * 32 + quad * 8];

    fill_wfrag(W2, flags[fiW2] != 0, wf, tid);
    __syncthreads();

#pragma unroll
    for (int ct = 0; ct < 8; ++ct) {
        f32x4 acc = {0.f, 0.f, 0.f, 0.f};
#pragma unroll
        for (int kk = 0; kk < 4; ++kk)
            acc = __builtin_amdgcn_mfma_f32_16x16x32_bf16(
                a2[kk], wv[(ct * 4 + kk) * 64 + lane], acc, 0, 0, 0);
        float bias = ldf(b2, ct * 16 + r, fB2);
#pragma unroll
        for (int gg = 0; gg < 4; ++gg) {
            int row = rowBase + quad * 4 + gg;
            if (row < N) {
                int col = ct * 16 + r;
                float v = lrelu(acc[gg] + bias);
                if (RESIDUAL) v += ldf(feat, (size_t)row * DDIM + col, fF);
                out[(size_t)row * DDIM + col] = v;
            }
        }
    }
}

extern "C" void kernel_launch(void* const* d_in, const int* in_sizes, int n_in,
                              void* d_out, int out_size, void* d_ws, size_t ws_size,
                              hipStream_t stream)
{
    const int* src_c2r = (const int*)d_in[2];
    const int* dst_c2r = (const int*)d_in[3];
    const int* src_r2c = (const int*)d_in[5];
    const int* dst_r2c = (const int*)d_in[6];
    const int nE = in_sizes[2];

    char* wsb = (char*)d_ws;
    int*    flags  = (int*)wsb;
    __bf16* wfprep = (__bf16*)(wsb + 128);

    // ---- A8 layout: cntA|ovCntA|cntB|ovCntB|slots2A|slots2B|ovLA|ovLB|cbufX|cbufH
    int*    cntA   = (int*)(wsb + 128 + 131072);
    int*    ovCntA = cntA + NROW;
    int*    cntB   = cntA + NROW + 8;
    int*    ovCntB = cntA + 2 * NROW + 8;
    size_t  o5 = 128 + 131072 + ((size_t)2 * NROW + 16) * 4;
    o5 = (o5 + 15) & ~(size_t)15;
    int2*   sl2A = (int2*)(wsb + o5);  o5 += (size_t)NROW * CAP * 8;
    int2*   sl2B = (int2*)(wsb + o5);  o5 += (size_t)NROW * CAP * 8;
    int*    ovLA = (int*)(wsb + o5);   o5 += (size_t)nE * 4;
    int*    ovLB = (int*)(wsb + o5);   o5 += (size_t)nE * 4;
    o5 = (o5 + 15) & ~(size_t)15;
    __bf16* cbX  = (__bf16*)(wsb + o5); o5 += (size_t)NCOL * DDIM * 2;
    __bf16* cbH  = (__bf16*)(wsb + o5); o5 += (size_t)NROW * DDIM * 2;
    const size_t NEED_A8 = o5;

    // ---- A2 (round-7) layout: cntA|ovCntA|cntB|ovCntB|slots2|ovLA|ovLB|cbuf
    size_t  ofsA2   = 128 + 131072 + ((size_t)2 * NROW + 16) * 4;
    ofsA2 = (ofsA2 + 15) & ~(size_t)15;
    int2*   slots2A2  = (int2*)(wsb + ofsA2);
    size_t  ofsOvA2   = ofsA2 + (size_t)NROW * CAP * 8;
    int*    ovListA2  = (int*)(wsb + ofsOvA2);
    int*    ovListB2  = ovListA2 + nE;
    size_t  ofsCbA2   = (ofsOvA2 + (size_t)nE * 8 + 15) & ~(size_t)15;
    __bf16* cbufA2    = (__bf16*)(wsb + ofsCbA2);
    const size_t NEED_A2 = ofsCbA2 + (size_t)NROW * DDIM * 2;

    const bool tierA8 = ws_size >= NEED_A8;
    const bool tierA2 = ws_size >= NEED_A2;

    TensorTab T;
    for (int i = 0; i < 18; ++i) { T.p[i] = d_in[i]; T.n[i] = in_sizes[i]; }

    float* out_row = (float*)d_out;
    float* out_col = out_row + (size_t)NROW * DDIM;
    const size_t aggBytes = (size_t)NROW * DDIM * sizeof(float);

    const int eblocks  = (nE + 255) / 256;
    const int sblocks  = (nE * 32 + 255) / 256;
    const int mblocksR = (NROW + 63) / 64;
    const int mblocksC = (NCOL + 63) / 64;
    const int csR      = (NROW + 15) / 16;
    const int csC      = (NCOL + 15) / 16;
    const int gblocksR = (NROW + 3) / 4;
    const int gblocksC = (NCOL + 3) / 4;
    const int cblocks  = (NCOL * DDIM / 8 + 255) / 256;
    const int zn2      = 2 * NROW + 16;
    const int zb2      = (zn2 + 255) / 256;

    WPtrs P;
    P.W[0] = d_in[8];  P.fi[0] = 8;
    P.W[1] = d_in[10]; P.fi[1] = 10;
    P.W[2] = d_in[12]; P.fi[2] = 12;
    P.W[3] = d_in[14]; P.fi[3] = 14;

    if (tierA8) {
        const int n8  = NCOL * DDIM / 8;              // 800000
        const int cb4 = (n8 + 1023) / 1024;           // convert blocks (1024t)
        const int eb4 = (nE + 1023) / 1024;           // fill blocks (1024t, D2)
        // D1: detect dtypes || zero cntA/ovCntA/cntB/ovCntB
        detect_zero<<<18 + zb2, 256, 0, stream>>>(T, flags, cntA, zn2);
        // D2: convert cbufX || fillA (packed), interleaved 4:3; prep at tail
        {
            int ka = (cb4 + 3) / 4, kb = (eb4 + 2) / 3;
            int K = ka > kb ? ka : kb;
            prep_fill_i2<<<7 * K + 8, 1024, 0, stream>>>(
                P, flags, wfprep, d_in[1], cbX, n8, 1, cb4, eb4, 7 * K,
                dst_c2r, src_c2r, d_in[4], nE, cntA, sl2A, ovCntA, ovLA, 4);
        }
        // D3: segsumA (cbX -> out_col) || fillB, interleaved 4:3 (256t)
        {
            int ka = (gblocksR + 3) / 4, kb = (eblocks + 2) / 3;
            int K = ka > kb ? ka : kb;
            segsum_fill_i<<<7 * K, 256, 0, stream>>>(
                cbX, cntA, sl2A, out_col, NROW, src_c2r, dst_c2r, d_in[4],
                ovLA, ovCntA, flags, 4,
                gblocksR, eblocks, dst_r2c, src_r2c, d_in[7], nE, cntB,
                sl2B, ovCntB, ovLB, 7);
        }
        // D4: mlp1 (out_row = h+feat f32, cbufH = h bf16) — pure, no fill
        mlp_cs<true, true><<<csR, 256, 0, stream>>>(
            d_in[0], out_col, d_in[9], d_in[11], d_in[16],
            out_row, NROW, flags, 0, 9, 11, 16,
            wfprep + 0 * 16384, wfprep + 1 * 16384, cbH,
            csR, nullptr, nullptr, nullptr, 0, nullptr, nullptr,
            nullptr, nullptr, 0);
        // D5: segsumB (cbH -> out_col), no fill role
        segsum_fill_i<<<gblocksC, 256, 0, stream>>>(
            cbH, cntB, sl2B, out_col, NCOL, src_r2c, dst_r2c, d_in[7],
            ovLB, ovCntB, flags, 7,
            gblocksC, 0, nullptr, nullptr, nullptr, 0, nullptr,
            nullptr, nullptr, nullptr, 0);
        // D6: mlp2 -> out_col
        mlp_cs<true, false><<<csC, 256, 0, stream>>>(
            d_in[1], out_col, d_in[13], d_in[15], d_in[17],
            out_col, NCOL, flags, 1, 13, 15, 17,
            wfprep + 2 * 16384, wfprep + 3 * 16384, nullptr,
            csC, nullptr, nullptr, nullptr, 0, nullptr, nullptr,
            nullptr, nullptr, 0);
    } else if (tierA2) {
        // round-7 proven path (single slot buffer)
        detect_zero<<<18 + zb2, 256, 0, stream>>>(T, flags, cntA, zn2);
        prep_fill<<<cblocks + 32 + eblocks, 256, 0, stream>>>(
            P, flags, wfprep, d_in[1], cbufA2, NCOL * DDIM / 8, 1, cblocks,
            dst_c2r, src_c2r, d_in[4], nE, cntA, slots2A2, ovCntA,
            ovListA2, 4);
        segsum_fill_i<<<gblocksR, 256, 0, stream>>>(
            cbufA2, cntA, slots2A2, out_col, NROW, src_c2r, dst_c2r,
            d_in[4], ovListA2, ovCntA, flags, 4,
            gblocksR, 0, nullptr, nullptr, nullptr, 0, nullptr,
            nullptr, nullptr, nullptr, 0);
        mlp_cs<true, true><<<csR + eblocks, 256, 0, stream>>>(
            d_in[0], out_col, d_in[9], d_in[11], d_in[16],
            out_row, NROW, flags, 0, 9, 11, 16,
            wfprep + 0 * 16384, wfprep + 1 * 16384, cbufA2,
            csR, dst_r2c, src_r2c, d_in[7], nE, cntB, slots2A2,
            ovCntB, ovListB2, 7);
        segsum_fill_i<<<gblocksC, 256, 0, stream>>>(
            cbufA2, cntB, slots2A2, out_col, NCOL, src_r2c, dst_r2c,
            d_in[7], ovListB2, ovCntB, flags, 7,
            gblocksC, 0, nullptr, nullptr, nullptr, 0, nullptr,
            nullptr, nullptr, nullptr, 0);
        mlp_cs<true, false><<<csC, 256, 0, stream>>>(
            d_in[1], out_col, d_in[13], d_in[15], d_in[17],
            out_col, NCOL, flags, 1, 13, 15, 17,
            wfprep + 2 * 16384, wfprep + 3 * 16384, nullptr,
            csC, nullptr, nullptr, nullptr, 0, nullptr, nullptr,
            nullptr, nullptr, 0);
    } else {
        // legacy path
        detect_zero<<<18, 256, 0, stream>>>(T, flags, nullptr, 0);
        hipMemsetAsync(out_col, 0, aggBytes, stream);
        scatter_any<<<sblocks, 256, 0, stream>>>(d_in[1], src_c2r, dst_c2r,
            d_in[4], out_col, nE, flags, 1, 4);
        mlp_kernel<false><<<mblocksR, 256, 0, stream>>>(
            d_in[0], out_col, d_in[8], d_in[9], d_in[10], d_in[11], d_in[16],
            out_row, NROW, flags, 0, 8, 9, 10, 11, 16);

        hipMemsetAsync(out_col, 0, aggBytes, stream);
        scatter_any<<<sblocks, 256, 0, stream>>>(out_row, src_r2c, dst_r2c,
            d_in[7], out_col, nE, flags, -1, 7);
        residual_add<<<(NROW * DDIM / 4 + 255) / 256, 256, 0, stream>>>(
            out_row, d_in[0], NROW * DDIM / 4, flags, 0);
        mlp_kernel<true><<<mblocksC, 256, 0, stream>>>(
            d_in[1], out_col, d_in[12], d_in[13], d_in[14], d_in[15], d_in[17],
            out_col, NCOL, flags, 1, 12, 13, 14, 15, 17);
    }
}